// Round 14
// baseline (452.934 us; speedup 1.0000x reference)
//
#include <hip/hip_runtime.h>

#define N_ 32
#define C_ 64
#define T_ 256
#define V_ 25
#define O_ 192
#define S_ 3
#define R_ 8
#define VV (V_*V_)      // 625
#define TV (T_*V_)      // 6400
#define RP 26           // padded v-rows per t
#define TRP (T_*RP)     // 6656 rows per n

typedef unsigned short u16;
typedef unsigned int u32;
typedef __attribute__((ext_vector_type(4))) u16 u16x4;
typedef __attribute__((ext_vector_type(8))) u16 u16x8;
typedef __attribute__((ext_vector_type(4))) u32 u32x4;
typedef __attribute__((ext_vector_type(8))) __bf16 bf16x8;
typedef __attribute__((ext_vector_type(4))) float f32x4;

// ---- workspace layout (u16 units) ----
#define WS_A2F_U 0                                   // N*O*6*64*8 = 18,874,368
#define WS_XQ_U  (18874368)                          // 13,631,488
#define WS_XD_U  (18874368 + 13631488)               // 39,321,600
#define WS_YB_U  (18874368 + 13631488 + 39321600)    // 39,321,600 (y as bf16)
// float region (after 111,149,056 u16):
#define WS_XM_F   (55574528)                         // N*C*V = 51,200
#define WS_RS_F   (55574528 + 51200)                 // N*O*V = 153,600
#define WS_STAT_F (55574528 + 51200 + 153600)        // 4*O
#define WS_COEF_F (55574528 + 51200 + 153600 + 768)  // 4*O

__device__ __forceinline__ u16 f2b(float f) {
    return __builtin_bit_cast(u16, (__bf16)f);
}
__device__ __forceinline__ float b2f(u16 u) {
    return __builtin_bit_cast(float, ((unsigned)u) << 16);
}
__device__ __forceinline__ f32x4 mfma16(bf16x8 a, bf16x8 b, f32x4 c) {
    return __builtin_amdgcn_mfma_f32_16x16x32_bf16(a, b, c, 0, 0, 0);
}

// ---------------- K0: x[n,c,t,v] fp32 -> xq[n][t*26+v][c' perm] bf16 ----------------
__global__ void k0_xq(const float* __restrict__ x, u16* __restrict__ xq) {
    __shared__ float tile[64][52];
    int bid = blockIdx.x;
    int n = bid >> 7, tb = bid & 127;
    int t0 = tb * 2;
    int tid = threadIdx.x;
    const float2* xp = (const float2*)(x + (size_t)n * C_ * TV + t0 * 25);
    for (int p = tid; p < 1600; p += 256) {
        int c = p / 25, q = p % 25;
        float2 f2 = xp[(size_t)c * 3200 + q];
        tile[c][q * 2] = f2.x;
        tile[c][q * 2 + 1] = f2.y;
    }
    __syncthreads();
    for (int p = tid; p < 832; p += 256) {
        int row = p >> 4, c4g = p & 15;
        int t = row >= RP, v = row - t * RP;
        u16x4 w;
        #pragma unroll
        for (int i = 0; i < 4; ++i) {
            int co = ((c4g & 3) << 4) + ((c4g >> 2) << 2) + i;
            w[i] = (v < 25) ? f2b(tile[co][t * 25 + v]) : (u16)0;
        }
        *(u16x4*)&xq[((size_t)n * TRP + tb * 52 + row) * 64 + c4g * 4] = w;
    }
}

// ---------------- K1: xm[n,c,v] from xq (bf16, 26 MB) ----------------
__global__ void k1_xm(const u16* __restrict__ xq, float* __restrict__ xm_out) {
    __shared__ float ps[256];
    int bid = blockIdx.x;
    int n = bid / 25, v = bid % 25;
    int tid = threadIdx.x;
    int cg = tid & 63, tg = tid >> 6;
    const u16* p = xq + (size_t)n * TRP * 64 + ((size_t)(tg * 64 * RP + v)) * 64 + cg;
    float s = 0.f;
    for (int t = 0; t < 64; ++t) {
        s += b2f(*p);
        p += RP * 64;
    }
    ps[tid] = s;
    __syncthreads();
    if (tid < 64) {
        float tot = ps[tid] + ps[64 + tid] + ps[128 + tid] + ps[192 + tid];
        int c4g = tid >> 2, i = tid & 3;
        int co = ((c4g & 3) << 4) + ((c4g >> 2) << 2) + i;
        xm_out[((size_t)n * C_ + co) * V_ + v] = tot * (1.f / T_);
    }
}

// ---------------- K2: barrier-free per-wave A2F build + rs_tot ----------------
// grid N*S*8; block: shared dm phase (3 barriers), then each wave owns 3 o-pairs
// in a private aat region (wave-internal LDS ordering, no __syncthreads).
__global__ void k2_a2f(const float* __restrict__ spd, const float* __restrict__ A3,
                       const float* __restrict__ A6,
                       const float* __restrict__ w1, const float* __restrict__ b1,
                       const float* __restrict__ w2, const float* __restrict__ b2,
                       const float* __restrict__ w4, const float* __restrict__ b4,
                       const float* __restrict__ b3,
                       const float* __restrict__ alpha, const float* __restrict__ beta,
                       const float* __restrict__ gamma,
                       u16* __restrict__ a2f, const float* __restrict__ xmbuf,
                       float* __restrict__ rs_tot) {
    __shared__ float xm[C_ * V_];        // 6400 B
    __shared__ float x1s[R_ * V_], x2s[R_ * V_];
    __shared__ float dm[R_ * VV];        // 20000 B
    __shared__ float a3s[VV], sps[VV];   // 5000 B
    __shared__ float aatw[4][2 * VV];    // 20000 B  (per-wave regions)
    int bid = blockIdx.x;
    int n = bid / 24;
    int rem = bid % 24;
    int s = rem / 8, og = rem % 8;
    int tid = threadIdx.x, wid = tid >> 6, lane = tid & 63;
    const float* xmg = xmbuf + (size_t)n * C_ * V_;
    for (int p = tid; p < C_ * V_; p += 256) xm[p] = xmg[p];
    for (int p = tid; p < VV; p += 256) { a3s[p] = A3[s * VV + p]; sps[p] = spd[p]; }
    __syncthreads();
    if (tid < R_ * V_) {
        int r = tid / V_, v = tid % V_;
        float acc1 = b1[s * R_ + r], acc2 = b2[s * R_ + r];
        for (int c = 0; c < C_; ++c) {
            float xv = xm[c * V_ + v];
            acc1 += xv * w1[(s * R_ + r) * C_ + c];
            acc2 += xv * w2[(s * R_ + r) * C_ + c];
        }
        x1s[tid] = acc1; x2s[tid] = acc2;
    }
    __syncthreads();
    for (int p = tid; p < R_ * VV; p += 256) {
        int r = p / VV, uv = p % VV, u = uv / V_, v = uv % V_;
        dm[p] = tanhf(x1s[r * V_ + u] - x2s[r * V_ + v]);
    }
    __syncthreads();
    float al = alpha[0], be = beta[0], ga = gamma[0];
    float* aat = aatw[wid];
    for (int opi = 0; opi < 3; ++opi) {
        int op = wid * 3 + opi;
        int o0 = og * 24 + op * 2;
        // wave-uniform scalar loads
        float w4v[2][R_], b4v[2];
        #pragma unroll
        for (int oo = 0; oo < 2; ++oo) {
            b4v[oo] = b4[s * O_ + o0 + oo];
            #pragma unroll
            for (int r = 0; r < R_; ++r)
                w4v[oo][r] = w4[((size_t)(s * O_ + o0 + oo)) * R_ + r];
        }
        const float* a6p0 = A6 + ((o0 % 6) * VV);
        for (int p = lane; p < 2 * VV; p += 64) {
            int oo = p / VV, pp = p - oo * VV;
            float acc = b4v[oo];
            #pragma unroll
            for (int r = 0; r < R_; ++r) acc += dm[r * VV + pp] * w4v[oo][r];
            aat[p] = al * acc + a3s[pp] + ga * sps[pp] + be * a6p0[oo * VV + pp];
        }
        if (lane < 2 * V_) {
            int oo = lane / V_, u = lane - oo * V_;
            float rs = 0.f;
            for (int v = 0; v < V_; ++v) rs += aat[oo * VV + u * V_ + v];
            atomicAdd(&rs_tot[((size_t)(n * O_ + o0 + oo)) * V_ + u],
                      b3[s * O_ + o0 + oo] * rs);
        }
        #pragma unroll
        for (int it = 0; it < 4; ++it) {
            int idx = it * 64 + lane;
            int oo = idx >> 7, l2 = idx & 127, cu = l2 >> 6, l = l2 & 63;
            int u = cu * 16 + (l & 15);
            u16x8 w;
            #pragma unroll
            for (int j = 0; j < 8; ++j) {
                int v = ((j >> 2) << 4) + ((l >> 4) << 2) + (j & 3);
                float val = 0.f;
                if (u < V_ && v < V_) val = aat[oo * VV + u * V_ + v];
                w[j] = f2b(val);
            }
            size_t idxg = ((((size_t)(n * O_ + o0 + oo)) * S_ + s) * 2 + cu) * 64 + l;
            ((u16x8*)a2f)[idxg] = w;
        }
    }
}

// ---------------- K3: fused MFMA GEMM1+GEMM2 + down + stats ----------------
// t-split: grid N*48 = 1536, single x3 buffer (33.1 KB total -> 4 blocks/CU),
// 2 barriers/chunk, cross-barrier reg prefetch, staged coalesced bf16 stores.
#define OSTR_B 2504          // /4 = 626 ≡ 18 (mod 32)
#define SSTR_B 832           // 416 rows * 2B
#define BUF_B  20064         // 8*2504 + 32 pad

__global__ __launch_bounds__(256, 4)
void k3_main(const u16* __restrict__ xq,
             const float* __restrict__ w3, const float* __restrict__ dw,
             const float* __restrict__ db,
             const u16* __restrict__ a2f, const float* __restrict__ rs_tot,
             u16* __restrict__ yb16, u16* __restrict__ xdws,
             float* __restrict__ stats) {
    __shared__ char x3Lb[BUF_B];        // 20,064 B
    __shared__ u16 xdst[8 * 416];       //  6,656 B
    __shared__ u16 ystage[8 * 400];     //  6,400 B
    int orig = blockIdx.x;
    int bid = (orig & 7) * 192 + (orig >> 3);   // same-n blocks -> same XCD
    int n = bid / 48;
    int rem = bid % 48;
    int o0 = (rem >> 1) * 8;
    int th = rem & 1;
    int tid = threadIdx.x, wid = tid >> 6, lane = tid & 63;
    int lr = lane & 15, lg = lane >> 4;
    int colt = wid & 1;
    int rt0 = (wid >> 1) * 13;

    for (int p = tid; p < BUF_B / 16; p += 256) ((u32x4*)x3Lb)[p] = u32x4{0,0,0,0};

    // GEMM1 B-frags: colt0 cols = (s0,o0..7)|(s1,o0..7); colt1 = (s2,o0..7)|(down,o0..7)
    const float* wsrc = (colt == 0)
        ? w3 + ((size_t)((lr >> 3) * O_ + o0 + (lr & 7))) * C_
        : ((lr < 8) ? w3 + ((size_t)(2 * O_ + o0 + lr)) * C_
                    : dw + ((size_t)(o0 + lr - 8)) * C_);
    bf16x8 bw[2];
    #pragma unroll
    for (int ks = 0; ks < 2; ++ks) {
        u16x8 tmp;
        #pragma unroll
        for (int j = 0; j < 8; ++j) {
            int c = ks * 32 + (lg << 2) + (j & 3) + ((j >> 2) << 4);
            tmp[j] = f2b(wsrc[c]);
        }
        bw[ks] = __builtin_bit_cast(bf16x8, tmp);
    }
    float dbv = (colt == 1 && lr >= 8) ? db[o0 + lr - 8] : 0.f;

    int wo = (colt == 0) ? (lr & 7) : lr;
    int wsb = (colt == 0) ? (lr >> 3) : 2;
    int colbyte = wo * OSTR_B + wsb * SSTR_B;

    const bf16x8* a2v = (const bf16x8*)a2f;
    bf16x8 Bh[2][6];
    float rsb0[2], rsb1[2];
    #pragma unroll
    for (int oi = 0; oi < 2; ++oi) {
        int o = o0 + (wid << 1) + oi;
        const bf16x8* bp = a2v + ((size_t)(n * O_ + o)) * 6 * 64 + lane;
        #pragma unroll
        for (int q = 0; q < 6; ++q) Bh[oi][q] = bp[(size_t)q * 64];
        const float* rsp = rs_tot + ((size_t)(n * O_ + o)) * V_;
        rsb0[oi] = rsp[lr];
        rsb1[oi] = (lr < 9) ? rsp[16 + lr] : 0.f;
    }

    float sy1[2] = {0, 0}, sy2[2] = {0, 0};
    float sd1 = 0.f, sd2 = 0.f;
    const u16* xbn = xq + (size_t)n * TRP * 64;
    int rdw = 13 * lr + 2 * lg;
    char* buf = x3Lb;

    // tile loader (chunk ch in [0,8), local tile j)
    auto tl = [&](int ch, int j, u16x8& A0, u16x8& A1) {
        const u16* p = xbn + ((size_t)((th * 128 + ch * 16)) * RP
                              + (size_t)((rt0 + j) * 16 + lr)) * 64 + (lg << 4);
        A0 = *(const u16x8*)p;
        A1 = *(const u16x8*)(p + 8);
    };
    auto proc = [&](int rt, u16x8 A0, u16x8 A1) {
        f32x4 acc = {0.f, 0.f, 0.f, 0.f};
        acc = mfma16(__builtin_bit_cast(bf16x8, A0), bw[0], acc);
        acc = mfma16(__builtin_bit_cast(bf16x8, A1), bw[1], acc);
        int rbase = rt * 16 + (lg << 2);
        if (colt == 0 || lr < 8) {
            u16x4 w;
            #pragma unroll
            for (int reg = 0; reg < 4; ++reg) w[reg] = f2b(acc[reg]);
            *(u16x4*)(buf + colbyte + rbase * 2) = w;
        } else {
            u16x4 w;
            #pragma unroll
            for (int reg = 0; reg < 4; ++reg) {
                int rr = rbase + reg;
                int t = rr / RP, v = rr - t * RP;
                float val = acc[reg] + dbv;
                w[reg] = f2b(val);
                if (v < 25) { sd1 += val; sd2 += val * val; }
            }
            *(u16x4*)&xdst[(lr - 8) * 416 + rbase] = w;
        }
    };

    __syncthreads();                           // init fence

    u16x8 p0a, p0b, p1a, p1b, p2a, p2b, p3a, p3b;
    tl(0, 0, p0a, p0b); tl(0, 1, p1a, p1b); tl(0, 2, p2a, p2b); tl(0, 3, p3a, p3b);

    for (int ch = 0; ch < 8; ++ch) {
        int t0 = th * 128 + ch * 16;
        // ---- GEMM1: peeled prefetched tiles 0..3, then in-chunk 4..12
        proc(rt0 + 0, p0a, p0b);
        proc(rt0 + 1, p1a, p1b);
        proc(rt0 + 2, p2a, p2b);
        proc(rt0 + 3, p3a, p3b);
        for (int j = 4; j < 13; ++j) {
            u16x8 A0, A1;
            tl(ch, j, A0, A1);
            proc(rt0 + j, A0, A1);
        }
        // prefetch next chunk's tiles 0..3 (in flight across barrier + GEMM2)
        if (ch < 7) {
            tl(ch + 1, 0, p0a, p0b); tl(ch + 1, 1, p1a, p1b);
            tl(ch + 1, 2, p2a, p2b); tl(ch + 1, 3, p3a, p3b);
        }
        __syncthreads();   // GEMM1 -> GEMM2/compaction handoff
        // ---- GEMM2 -> ystage (bf16)
        #pragma unroll
        for (int oi = 0; oi < 2; ++oi) {
            int ol = (wid << 1) + oi;
            const u32* L = (const u32*)(buf + ol * OSTR_B);
            f32x4 acc0 = {0, 0, 0, 0}, acc1 = {0, 0, 0, 0};
            #pragma unroll
            for (int s = 0; s < 3; ++s) {
                const u32* Ls = L + s * 208 + rdw;
                u32 d0 = Ls[0], d1 = Ls[1], d8 = Ls[8], d9 = Ls[9];
                bf16x8 A = __builtin_bit_cast(bf16x8, u32x4{d0, d1, d8, d9});
                acc0 = mfma16(A, Bh[oi][s * 2 + 0], acc0);
                acc1 = mfma16(A, Bh[oi][s * 2 + 1], acc1);
            }
            int ylb = ol * 400 + (lg << 2) * 25;
            #pragma unroll
            for (int reg = 0; reg < 4; ++reg) {
                float v0 = acc0[reg] + rsb0[oi];
                ystage[ylb + reg * 25 + lr] = f2b(v0);
                sy1[oi] += v0; sy2[oi] += v0 * v0;
                if (lr < 9) {
                    float v1 = acc1[reg] + rsb1[oi];
                    ystage[ylb + reg * 25 + 16 + lr] = f2b(v1);
                    sy1[oi] += v1; sy2[oi] += v1 * v1;
                }
            }
        }
        // ---- per-wave y compaction: coalesced 16B stores of own 2 o's
        {
            size_t ygb = (size_t)(n * O_ + o0) * TV + (size_t)t0 * V_;
            for (int q = lane; q < 100; q += 64) {
                int sel = q >= 50;
                int ol2 = (wid << 1) + sel;
                int j = q - sel * 50;
                u16x8 pk = *(const u16x8*)&ystage[ol2 * 400 + j * 8];
                *(u16x8*)&yb16[ygb + (size_t)ol2 * TV + j * 8] = pk;
            }
        }
        // ---- per-wave xd compaction (colt1 waves own their staged halves)
        if (colt == 1) {
            int tofs = (wid >> 1) * 8;
            size_t gdb = (size_t)(n * O_ + o0) * TV + (size_t)(t0 + tofs) * V_;
            for (int q = lane; q < 200; q += 64) {
                int o = q / 25, w = q - o * 25;
                int g0 = w * 8;
                int tl2 = g0 / 25, v = g0 - tl2 * 25;
                u16x8 pk;
                #pragma unroll
                for (int k = 0; k < 8; ++k) {
                    pk[k] = xdst[o * 416 + (tofs + tl2) * RP + v];
                    if (++v == 25) { v = 0; ++tl2; }
                }
                *(u16x8*)&xdws[gdb + (size_t)o * TV + g0] = pk;
            }
        }
        __syncthreads();   // readers done before next GEMM1 overwrites LDS
    }
    // stats -> global atomics
    #pragma unroll
    for (int oi = 0; oi < 2; ++oi) {
        float v1 = sy1[oi], v2 = sy2[oi];
        #pragma unroll
        for (int m = 1; m < 64; m <<= 1) {
            v1 += __shfl_xor(v1, m);
            v2 += __shfl_xor(v2, m);
        }
        if (lane == 0) {
            atomicAdd(&stats[0 * O_ + o0 + (wid << 1) + oi], v1);
            atomicAdd(&stats[1 * O_ + o0 + (wid << 1) + oi], v2);
        }
    }
    if (colt == 1) {
        float v1 = sd1, v2 = sd2;
        v1 += __shfl_xor(v1, 16); v2 += __shfl_xor(v2, 16);
        v1 += __shfl_xor(v1, 32); v2 += __shfl_xor(v2, 32);
        if (lane >= 8 && lane < 16) {
            atomicAdd(&stats[2 * O_ + o0 + lane - 8], v1);
            atomicAdd(&stats[3 * O_ + o0 + lane - 8], v2);
        }
    }
}

// ---------------- K4: BN coefficients ----------------
__global__ void k4_coef(const float* __restrict__ bn_w, const float* __restrict__ bn_b,
                        const float* __restrict__ dbn_w, const float* __restrict__ dbn_b,
                        const float* __restrict__ stats, float* __restrict__ coef) {
    int o = threadIdx.x;
    if (o >= O_) return;
    float inv = 1.f / (float)(N_ * T_ * V_);
    float mu_y = stats[o] * inv;
    float var_y = stats[O_ + o] * inv - mu_y * mu_y;
    float ay = bn_w[o] * rsqrtf(var_y + 1e-5f);
    float by = bn_b[o] - mu_y * ay;
    float mu_d = stats[2 * O_ + o] * inv;
    float var_d = stats[3 * O_ + o] * inv - mu_d * mu_d;
    float ad = dbn_w[o] * rsqrtf(var_d + 1e-5f);
    float bd = dbn_b[o] - mu_d * ad;
    coef[o] = ay; coef[O_ + o] = by; coef[2 * O_ + o] = ad; coef[3 * O_ + o] = bd;
}

// ---------------- K5: final BN+residual+relu (y bf16 + xd bf16 -> out fp32) ----------------
__global__ void k5_final(float* __restrict__ out, const u16* __restrict__ yb,
                         const u16* __restrict__ xd, const float* __restrict__ cf) {
    size_t total = (size_t)N_ * O_ * TV / 8;
    for (size_t i = blockIdx.x * (size_t)blockDim.x + threadIdx.x; i < total;
         i += (size_t)gridDim.x * blockDim.x) {
        int o = (int)((i / 800) % O_);
        float ay = cf[o], by = cf[O_ + o], ad = cf[2 * O_ + o], bd = cf[3 * O_ + o];
        u16x8 yv = ((const u16x8*)yb)[i];
        u16x8 dv = ((const u16x8*)xd)[i];
        float4 r0, r1;
        r0.x = fmaxf(ay * b2f(yv[0]) + by + ad * b2f(dv[0]) + bd, 0.f);
        r0.y = fmaxf(ay * b2f(yv[1]) + by + ad * b2f(dv[1]) + bd, 0.f);
        r0.z = fmaxf(ay * b2f(yv[2]) + by + ad * b2f(dv[2]) + bd, 0.f);
        r0.w = fmaxf(ay * b2f(yv[3]) + by + ad * b2f(dv[3]) + bd, 0.f);
        r1.x = fmaxf(ay * b2f(yv[4]) + by + ad * b2f(dv[4]) + bd, 0.f);
        r1.y = fmaxf(ay * b2f(yv[5]) + by + ad * b2f(dv[5]) + bd, 0.f);
        r1.z = fmaxf(ay * b2f(yv[6]) + by + ad * b2f(dv[6]) + bd, 0.f);
        r1.w = fmaxf(ay * b2f(yv[7]) + by + ad * b2f(dv[7]) + bd, 0.f);
        ((float4*)out)[2 * i] = r0;
        ((float4*)out)[2 * i + 1] = r1;
    }
}

extern "C" void kernel_launch(void* const* d_in, const int* in_sizes, int n_in,
                              void* d_out, int out_size, void* d_ws, size_t ws_size,
                              hipStream_t stream) {
    const float* x     = (const float*)d_in[0];
    const float* spd   = (const float*)d_in[1];
    const float* A3    = (const float*)d_in[2];
    const float* A6    = (const float*)d_in[3];
    const float* w1    = (const float*)d_in[4];
    const float* b1    = (const float*)d_in[5];
    const float* w2    = (const float*)d_in[6];
    const float* b2    = (const float*)d_in[7];
    const float* w4    = (const float*)d_in[8];
    const float* b4    = (const float*)d_in[9];
    const float* w3    = (const float*)d_in[10];
    const float* b3    = (const float*)d_in[11];
    const float* alpha = (const float*)d_in[12];
    const float* beta  = (const float*)d_in[13];
    const float* gamma = (const float*)d_in[14];
    const float* bn_w  = (const float*)d_in[15];
    const float* bn_b  = (const float*)d_in[16];
    const float* dw    = (const float*)d_in[17];
    const float* db    = (const float*)d_in[18];
    const float* dbn_w = (const float*)d_in[19];
    const float* dbn_b = (const float*)d_in[20];
    float* out = (float*)d_out;
    u16*   wsu = (u16*)d_ws;
    float* wsf = (float*)d_ws;

    u16* a2f  = wsu + WS_A2F_U;
    u16* xq   = wsu + WS_XQ_U;
    u16* xd   = wsu + WS_XD_U;
    u16* yb   = wsu + WS_YB_U;
    float* xm    = wsf + WS_XM_F;
    float* rs    = wsf + WS_RS_F;
    float* stats = wsf + WS_STAT_F;
    float* coef  = wsf + WS_COEF_F;

    // zero rs_tot + stats (contiguous) — accumulated via atomics each call
    hipMemsetAsync(rs, 0, (N_ * O_ * V_ + 4 * O_) * sizeof(float), stream);

    k0_xq<<<N_ * 128, 256, 0, stream>>>(x, xq);
    k1_xm<<<N_ * 25, 256, 0, stream>>>(xq, xm);
    k2_a2f<<<N_ * S_ * 8, 256, 0, stream>>>(spd, A3, A6, w1, b1, w2, b2, w4, b4, b3,
                                            alpha, beta, gamma, a2f, xm, rs);
    k3_main<<<N_ * 48, 256, 0, stream>>>(xq, w3, dw, db, a2f, rs, yb, xd, stats);
    k4_coef<<<1, 256, 0, stream>>>(bn_w, bn_b, dbn_w, dbn_b, stats, coef);
    k5_final<<<4096, 256, 0, stream>>>(out, yb, xd, coef);
}

// Round 15
// 338.733 us; speedup vs baseline: 1.3371x; 1.3371x over previous
//
#include <hip/hip_runtime.h>

#define N_ 32
#define C_ 64
#define T_ 256
#define V_ 25
#define O_ 192
#define S_ 3
#define R_ 8
#define VV (V_*V_)      // 625
#define TV (T_*V_)      // 6400
#define RP 26           // padded v-rows per t
#define TRP (T_*RP)     // 6656 rows per n

typedef unsigned short u16;
typedef unsigned int u32;
typedef __attribute__((ext_vector_type(4))) u16 u16x4;
typedef __attribute__((ext_vector_type(8))) u16 u16x8;
typedef __attribute__((ext_vector_type(4))) u32 u32x4;
typedef __attribute__((ext_vector_type(8))) __bf16 bf16x8;
typedef __attribute__((ext_vector_type(4))) float f32x4;

// ---- workspace layout (u16 units) ----
#define WS_A2F_U 0                                   // N*O*6*64*8 = 18,874,368
#define WS_XQ_U  (18874368)                          // 13,631,488
#define WS_XD_U  (18874368 + 13631488)               // 39,321,600
#define WS_YB_U  (18874368 + 13631488 + 39321600)    // 39,321,600 (y as bf16)
// float region (after 111,149,056 u16):
#define WS_XM_F   (55574528)                         // N*C*V = 51,200
#define WS_RS_F   (55574528 + 51200)                 // N*O*V = 153,600
#define WS_STAT_F (55574528 + 51200 + 153600)        // 4*O
#define WS_COEF_F (55574528 + 51200 + 153600 + 768)  // 4*O

__device__ __forceinline__ u16 f2b(float f) {
    return __builtin_bit_cast(u16, (__bf16)f);
}
__device__ __forceinline__ float b2f(u16 u) {
    return __builtin_bit_cast(float, ((unsigned)u) << 16);
}
__device__ __forceinline__ f32x4 mfma16(bf16x8 a, bf16x8 b, f32x4 c) {
    return __builtin_amdgcn_mfma_f32_16x16x32_bf16(a, b, c, 0, 0, 0);
}

// ---------------- K0: x[n,c,t,v] fp32 -> xq[n][t*26+v][c' perm] bf16 ----------------
__global__ void k0_xq(const float* __restrict__ x, u16* __restrict__ xq) {
    __shared__ float tile[64][52];
    int bid = blockIdx.x;
    int n = bid >> 7, tb = bid & 127;
    int t0 = tb * 2;
    int tid = threadIdx.x;
    const float2* xp = (const float2*)(x + (size_t)n * C_ * TV + t0 * 25);
    for (int p = tid; p < 1600; p += 256) {
        int c = p / 25, q = p % 25;
        float2 f2 = xp[(size_t)c * 3200 + q];
        tile[c][q * 2] = f2.x;
        tile[c][q * 2 + 1] = f2.y;
    }
    __syncthreads();
    for (int p = tid; p < 832; p += 256) {
        int row = p >> 4, c4g = p & 15;
        int t = row >= RP, v = row - t * RP;
        u16x4 w;
        #pragma unroll
        for (int i = 0; i < 4; ++i) {
            int co = ((c4g & 3) << 4) + ((c4g >> 2) << 2) + i;
            w[i] = (v < 25) ? f2b(tile[co][t * 25 + v]) : (u16)0;
        }
        *(u16x4*)&xq[((size_t)n * TRP + tb * 52 + row) * 64 + c4g * 4] = w;
    }
}

// ---------------- K1: xm[n,c,v] from xq (bf16, 26 MB) ----------------
__global__ void k1_xm(const u16* __restrict__ xq, float* __restrict__ xm_out) {
    __shared__ float ps[256];
    int bid = blockIdx.x;
    int n = bid / 25, v = bid % 25;
    int tid = threadIdx.x;
    int cg = tid & 63, tg = tid >> 6;
    const u16* p = xq + (size_t)n * TRP * 64 + ((size_t)(tg * 64 * RP + v)) * 64 + cg;
    float s = 0.f;
    for (int t = 0; t < 64; ++t) {
        s += b2f(*p);
        p += RP * 64;
    }
    ps[tid] = s;
    __syncthreads();
    if (tid < 64) {
        float tot = ps[tid] + ps[64 + tid] + ps[128 + tid] + ps[192 + tid];
        int c4g = tid >> 2, i = tid & 3;
        int co = ((c4g & 3) << 4) + ((c4g >> 2) << 2) + i;
        xm_out[((size_t)n * C_ + co) * V_ + v] = tot * (1.f / T_);
    }
}

// ---------------- K2: barrier-free per-wave A2F build + rs_tot (R14 version) ----------------
__global__ void k2_a2f(const float* __restrict__ spd, const float* __restrict__ A3,
                       const float* __restrict__ A6,
                       const float* __restrict__ w1, const float* __restrict__ b1,
                       const float* __restrict__ w2, const float* __restrict__ b2,
                       const float* __restrict__ w4, const float* __restrict__ b4,
                       const float* __restrict__ b3,
                       const float* __restrict__ alpha, const float* __restrict__ beta,
                       const float* __restrict__ gamma,
                       u16* __restrict__ a2f, const float* __restrict__ xmbuf,
                       float* __restrict__ rs_tot) {
    __shared__ float xm[C_ * V_];
    __shared__ float x1s[R_ * V_], x2s[R_ * V_];
    __shared__ float dm[R_ * VV];
    __shared__ float a3s[VV], sps[VV];
    __shared__ float aatw[4][2 * VV];
    int bid = blockIdx.x;
    int n = bid / 24;
    int rem = bid % 24;
    int s = rem / 8, og = rem % 8;
    int tid = threadIdx.x, wid = tid >> 6, lane = tid & 63;
    const float* xmg = xmbuf + (size_t)n * C_ * V_;
    for (int p = tid; p < C_ * V_; p += 256) xm[p] = xmg[p];
    for (int p = tid; p < VV; p += 256) { a3s[p] = A3[s * VV + p]; sps[p] = spd[p]; }
    __syncthreads();
    if (tid < R_ * V_) {
        int r = tid / V_, v = tid % V_;
        float acc1 = b1[s * R_ + r], acc2 = b2[s * R_ + r];
        for (int c = 0; c < C_; ++c) {
            float xv = xm[c * V_ + v];
            acc1 += xv * w1[(s * R_ + r) * C_ + c];
            acc2 += xv * w2[(s * R_ + r) * C_ + c];
        }
        x1s[tid] = acc1; x2s[tid] = acc2;
    }
    __syncthreads();
    for (int p = tid; p < R_ * VV; p += 256) {
        int r = p / VV, uv = p % VV, u = uv / V_, v = uv % V_;
        dm[p] = tanhf(x1s[r * V_ + u] - x2s[r * V_ + v]);
    }
    __syncthreads();
    float al = alpha[0], be = beta[0], ga = gamma[0];
    float* aat = aatw[wid];
    for (int opi = 0; opi < 3; ++opi) {
        int op = wid * 3 + opi;
        int o0 = og * 24 + op * 2;
        float w4v[2][R_], b4v[2];
        #pragma unroll
        for (int oo = 0; oo < 2; ++oo) {
            b4v[oo] = b4[s * O_ + o0 + oo];
            #pragma unroll
            for (int r = 0; r < R_; ++r)
                w4v[oo][r] = w4[((size_t)(s * O_ + o0 + oo)) * R_ + r];
        }
        const float* a6p0 = A6 + ((o0 % 6) * VV);
        for (int p = lane; p < 2 * VV; p += 64) {
            int oo = p / VV, pp = p - oo * VV;
            float acc = b4v[oo];
            #pragma unroll
            for (int r = 0; r < R_; ++r) acc += dm[r * VV + pp] * w4v[oo][r];
            aat[p] = al * acc + a3s[pp] + ga * sps[pp] + be * a6p0[oo * VV + pp];
        }
        if (lane < 2 * V_) {
            int oo = lane / V_, u = lane - oo * V_;
            float rs = 0.f;
            for (int v = 0; v < V_; ++v) rs += aat[oo * VV + u * V_ + v];
            atomicAdd(&rs_tot[((size_t)(n * O_ + o0 + oo)) * V_ + u],
                      b3[s * O_ + o0 + oo] * rs);
        }
        #pragma unroll
        for (int it = 0; it < 4; ++it) {
            int idx = it * 64 + lane;
            int oo = idx >> 7, l2 = idx & 127, cu = l2 >> 6, l = l2 & 63;
            int u = cu * 16 + (l & 15);
            u16x8 w;
            #pragma unroll
            for (int j = 0; j < 8; ++j) {
                int v = ((j >> 2) << 4) + ((l >> 4) << 2) + (j & 3);
                float val = 0.f;
                if (u < V_ && v < V_) val = aat[oo * VV + u * V_ + v];
                w[j] = f2b(val);
            }
            size_t idxg = ((((size_t)(n * O_ + o0 + oo)) * S_ + s) * 2 + cu) * 64 + l;
            ((u16x8*)a2f)[idxg] = w;
        }
    }
}

// ---------------- K3: R13 champion (768-block convoy, dbuf) + depth-6 prefetch ----------------
#define OSTR_B 2504          // /4 = 626 ≡ 18 (mod 32)
#define SSTR_B 832           // 416 rows * 2B
#define BUF_B  20064         // 8*2504 + 32 pad

__global__ __launch_bounds__(256, 3)
void k3_main(const u16* __restrict__ xq,
             const float* __restrict__ w3, const float* __restrict__ dw,
             const float* __restrict__ db,
             const u16* __restrict__ a2f, const float* __restrict__ rs_tot,
             u16* __restrict__ yb16, u16* __restrict__ xdws,
             float* __restrict__ stats) {
    __shared__ char x3Lb[2 * BUF_B];    // 40,128 B
    __shared__ u16 xdst[8 * 416];       //  6,656 B
    __shared__ u16 ystage[8 * 400];     //  6,400 B
    int orig = blockIdx.x;
    int bid = (orig & 7) * 96 + (orig >> 3);   // same-n blocks -> same XCD
    int n = bid / 24;
    int o0 = (bid % 24) * 8;
    int tid = threadIdx.x, wid = tid >> 6, lane = tid & 63;
    int lr = lane & 15, lg = lane >> 4;
    int colt = wid & 1;
    int rt0 = (wid >> 1) * 13;

    for (int p = tid; p < 2 * BUF_B / 16; p += 256) ((u32x4*)x3Lb)[p] = u32x4{0,0,0,0};

    const float* wsrc = (colt == 0)
        ? w3 + ((size_t)((lr >> 3) * O_ + o0 + (lr & 7))) * C_
        : ((lr < 8) ? w3 + ((size_t)(2 * O_ + o0 + lr)) * C_
                    : dw + ((size_t)(o0 + lr - 8)) * C_);
    bf16x8 bw[2];
    #pragma unroll
    for (int ks = 0; ks < 2; ++ks) {
        u16x8 tmp;
        #pragma unroll
        for (int j = 0; j < 8; ++j) {
            int c = ks * 32 + (lg << 2) + (j & 3) + ((j >> 2) << 4);
            tmp[j] = f2b(wsrc[c]);
        }
        bw[ks] = __builtin_bit_cast(bf16x8, tmp);
    }
    float dbv = (colt == 1 && lr >= 8) ? db[o0 + lr - 8] : 0.f;

    int wo = (colt == 0) ? (lr & 7) : lr;
    int wsb = (colt == 0) ? (lr >> 3) : 2;
    int colbyte = wo * OSTR_B + wsb * SSTR_B;

    const bf16x8* a2v = (const bf16x8*)a2f;
    bf16x8 Bh[2][6];
    float rsb0[2], rsb1[2];
    #pragma unroll
    for (int oi = 0; oi < 2; ++oi) {
        int o = o0 + (wid << 1) + oi;
        const bf16x8* bp = a2v + ((size_t)(n * O_ + o)) * 6 * 64 + lane;
        #pragma unroll
        for (int q = 0; q < 6; ++q) Bh[oi][q] = bp[(size_t)q * 64];
        const float* rsp = rs_tot + ((size_t)(n * O_ + o)) * V_;
        rsb0[oi] = rsp[lr];
        rsb1[oi] = (lr < 9) ? rsp[16 + lr] : 0.f;
    }

    float sy1[2] = {0, 0}, sy2[2] = {0, 0};
    float sd1 = 0.f, sd2 = 0.f;
    const u16* xbn = xq + (size_t)n * TRP * 64;
    int rdw = 13 * lr + 2 * lg;
    char* buf = x3Lb;
    int t0 = 0;

    auto tl = [&](int ch, int j, u16x8& A0, u16x8& A1) {
        const u16* p = xbn + ((size_t)(ch * 16) * RP + (size_t)((rt0 + j) * 16 + lr)) * 64
                       + (lg << 4);
        A0 = *(const u16x8*)p;
        A1 = *(const u16x8*)(p + 8);
    };
    auto proc = [&](int rt, u16x8 A0, u16x8 A1) {
        f32x4 acc = {0.f, 0.f, 0.f, 0.f};
        acc = mfma16(__builtin_bit_cast(bf16x8, A0), bw[0], acc);
        acc = mfma16(__builtin_bit_cast(bf16x8, A1), bw[1], acc);
        int rbase = rt * 16 + (lg << 2);
        if (colt == 0 || lr < 8) {
            u16x4 w;
            #pragma unroll
            for (int reg = 0; reg < 4; ++reg) w[reg] = f2b(acc[reg]);
            *(u16x4*)(buf + colbyte + rbase * 2) = w;
        } else {
            u16x4 w;
            #pragma unroll
            for (int reg = 0; reg < 4; ++reg) {
                int rr = rbase + reg;
                int t = rr / RP, v = rr - t * RP;
                float val = acc[reg] + dbv;
                w[reg] = f2b(val);
                if (v < 25) { sd1 += val; sd2 += val * val; }
            }
            *(u16x4*)&xdst[(lr - 8) * 416 + rbase] = w;
        }
    };

    __syncthreads();                           // init fence

    u16x8 p0a, p0b, p1a, p1b, p2a, p2b, p3a, p3b, p4a, p4b, p5a, p5b;
    tl(0, 0, p0a, p0b); tl(0, 1, p1a, p1b); tl(0, 2, p2a, p2b);
    tl(0, 3, p3a, p3b); tl(0, 4, p4a, p4b); tl(0, 5, p5a, p5b);

    for (int ch = 0; ch < 16; ++ch) {
        t0 = ch * 16;
        buf = x3Lb + (ch & 1) * BUF_B;
        // ---- GEMM1: peeled prefetched tiles 0..5, then in-chunk 6..12
        proc(rt0 + 0, p0a, p0b);
        proc(rt0 + 1, p1a, p1b);
        proc(rt0 + 2, p2a, p2b);
        proc(rt0 + 3, p3a, p3b);
        proc(rt0 + 4, p4a, p4b);
        proc(rt0 + 5, p5a, p5b);
        for (int j = 6; j < 13; ++j) {
            u16x8 A0, A1;
            tl(ch, j, A0, A1);
            proc(rt0 + j, A0, A1);
        }
        // prefetch next chunk's tiles 0..5 (in flight across barrier + GEMM2)
        if (ch < 15) {
            tl(ch + 1, 0, p0a, p0b); tl(ch + 1, 1, p1a, p1b);
            tl(ch + 1, 2, p2a, p2b); tl(ch + 1, 3, p3a, p3b);
            tl(ch + 1, 4, p4a, p4b); tl(ch + 1, 5, p5a, p5b);
        }
        __syncthreads();   // x3/xdst handoff; dbuf covers write-after-read
        // ---- GEMM2 -> ystage (bf16)
        #pragma unroll
        for (int oi = 0; oi < 2; ++oi) {
            int ol = (wid << 1) + oi;
            const u32* L = (const u32*)(buf + ol * OSTR_B);
            f32x4 acc0 = {0, 0, 0, 0}, acc1 = {0, 0, 0, 0};
            #pragma unroll
            for (int s = 0; s < 3; ++s) {
                const u32* Ls = L + s * 208 + rdw;
                u32 d0 = Ls[0], d1 = Ls[1], d8 = Ls[8], d9 = Ls[9];
                bf16x8 A = __builtin_bit_cast(bf16x8, u32x4{d0, d1, d8, d9});
                acc0 = mfma16(A, Bh[oi][s * 2 + 0], acc0);
                acc1 = mfma16(A, Bh[oi][s * 2 + 1], acc1);
            }
            int ylb = ol * 400 + (lg << 2) * 25;
            #pragma unroll
            for (int reg = 0; reg < 4; ++reg) {
                float v0 = acc0[reg] + rsb0[oi];
                ystage[ylb + reg * 25 + lr] = f2b(v0);
                sy1[oi] += v0; sy2[oi] += v0 * v0;
                if (lr < 9) {
                    float v1 = acc1[reg] + rsb1[oi];
                    ystage[ylb + reg * 25 + 16 + lr] = f2b(v1);
                    sy1[oi] += v1; sy2[oi] += v1 * v1;
                }
            }
        }
        // ---- per-wave y compaction: coalesced 16B stores of own 2 o's
        {
            size_t ygb = (size_t)(n * O_ + o0) * TV + (size_t)t0 * V_;
            for (int q = lane; q < 100; q += 64) {
                int sel = q >= 50;
                int ol2 = (wid << 1) + sel;
                int j = q - sel * 50;
                u16x8 pk = *(const u16x8*)&ystage[ol2 * 400 + j * 8];
                *(u16x8*)&yb16[ygb + (size_t)ol2 * TV + j * 8] = pk;
            }
        }
        // ---- per-wave xd compaction (colt1 waves own their staged halves)
        if (colt == 1) {
            int tofs = (wid >> 1) * 8;
            size_t gdb = (size_t)(n * O_ + o0) * TV + (size_t)(t0 + tofs) * V_;
            for (int q = lane; q < 200; q += 64) {
                int o = q / 25, w = q - o * 25;
                int g0 = w * 8;
                int tl2 = g0 / 25, v = g0 - tl2 * 25;
                u16x8 pk;
                #pragma unroll
                for (int k = 0; k < 8; ++k) {
                    pk[k] = xdst[o * 416 + (tofs + tl2) * RP + v];
                    if (++v == 25) { v = 0; ++tl2; }
                }
                *(u16x8*)&xdws[gdb + (size_t)o * TV + g0] = pk;
            }
        }
    }
    // stats -> global atomics
    #pragma unroll
    for (int oi = 0; oi < 2; ++oi) {
        float v1 = sy1[oi], v2 = sy2[oi];
        #pragma unroll
        for (int m = 1; m < 64; m <<= 1) {
            v1 += __shfl_xor(v1, m);
            v2 += __shfl_xor(v2, m);
        }
        if (lane == 0) {
            atomicAdd(&stats[0 * O_ + o0 + (wid << 1) + oi], v1);
            atomicAdd(&stats[1 * O_ + o0 + (wid << 1) + oi], v2);
        }
    }
    if (colt == 1) {
        float v1 = sd1, v2 = sd2;
        v1 += __shfl_xor(v1, 16); v2 += __shfl_xor(v2, 16);
        v1 += __shfl_xor(v1, 32); v2 += __shfl_xor(v2, 32);
        if (lane >= 8 && lane < 16) {
            atomicAdd(&stats[2 * O_ + o0 + lane - 8], v1);
            atomicAdd(&stats[3 * O_ + o0 + lane - 8], v2);
        }
    }
}

// ---------------- K4: BN coefficients ----------------
__global__ void k4_coef(const float* __restrict__ bn_w, const float* __restrict__ bn_b,
                        const float* __restrict__ dbn_w, const float* __restrict__ dbn_b,
                        const float* __restrict__ stats, float* __restrict__ coef) {
    int o = threadIdx.x;
    if (o >= O_) return;
    float inv = 1.f / (float)(N_ * T_ * V_);
    float mu_y = stats[o] * inv;
    float var_y = stats[O_ + o] * inv - mu_y * mu_y;
    float ay = bn_w[o] * rsqrtf(var_y + 1e-5f);
    float by = bn_b[o] - mu_y * ay;
    float mu_d = stats[2 * O_ + o] * inv;
    float var_d = stats[3 * O_ + o] * inv - mu_d * mu_d;
    float ad = dbn_w[o] * rsqrtf(var_d + 1e-5f);
    float bd = dbn_b[o] - mu_d * ad;
    coef[o] = ay; coef[O_ + o] = by; coef[2 * O_ + o] = ad; coef[3 * O_ + o] = bd;
}

// ---------------- K5: final BN+residual+relu (y bf16 + xd bf16 -> out fp32) ----------------
__global__ void k5_final(float* __restrict__ out, const u16* __restrict__ yb,
                         const u16* __restrict__ xd, const float* __restrict__ cf) {
    size_t total = (size_t)N_ * O_ * TV / 8;
    for (size_t i = blockIdx.x * (size_t)blockDim.x + threadIdx.x; i < total;
         i += (size_t)gridDim.x * blockDim.x) {
        int o = (int)((i / 800) % O_);
        float ay = cf[o], by = cf[O_ + o], ad = cf[2 * O_ + o], bd = cf[3 * O_ + o];
        u16x8 yv = ((const u16x8*)yb)[i];
        u16x8 dv = ((const u16x8*)xd)[i];
        float4 r0, r1;
        r0.x = fmaxf(ay * b2f(yv[0]) + by + ad * b2f(dv[0]) + bd, 0.f);
        r0.y = fmaxf(ay * b2f(yv[1]) + by + ad * b2f(dv[1]) + bd, 0.f);
        r0.z = fmaxf(ay * b2f(yv[2]) + by + ad * b2f(dv[2]) + bd, 0.f);
        r0.w = fmaxf(ay * b2f(yv[3]) + by + ad * b2f(dv[3]) + bd, 0.f);
        r1.x = fmaxf(ay * b2f(yv[4]) + by + ad * b2f(dv[4]) + bd, 0.f);
        r1.y = fmaxf(ay * b2f(yv[5]) + by + ad * b2f(dv[5]) + bd, 0.f);
        r1.z = fmaxf(ay * b2f(yv[6]) + by + ad * b2f(dv[6]) + bd, 0.f);
        r1.w = fmaxf(ay * b2f(yv[7]) + by + ad * b2f(dv[7]) + bd, 0.f);
        ((float4*)out)[2 * i] = r0;
        ((float4*)out)[2 * i + 1] = r1;
    }
}

extern "C" void kernel_launch(void* const* d_in, const int* in_sizes, int n_in,
                              void* d_out, int out_size, void* d_ws, size_t ws_size,
                              hipStream_t stream) {
    const float* x     = (const float*)d_in[0];
    const float* spd   = (const float*)d_in[1];
    const float* A3    = (const float*)d_in[2];
    const float* A6    = (const float*)d_in[3];
    const float* w1    = (const float*)d_in[4];
    const float* b1    = (const float*)d_in[5];
    const float* w2    = (const float*)d_in[6];
    const float* b2    = (const float*)d_in[7];
    const float* w4    = (const float*)d_in[8];
    const float* b4    = (const float*)d_in[9];
    const float* w3    = (const float*)d_in[10];
    const float* b3    = (const float*)d_in[11];
    const float* alpha = (const float*)d_in[12];
    const float* beta  = (const float*)d_in[13];
    const float* gamma = (const float*)d_in[14];
    const float* bn_w  = (const float*)d_in[15];
    const float* bn_b  = (const float*)d_in[16];
    const float* dw    = (const float*)d_in[17];
    const float* db    = (const float*)d_in[18];
    const float* dbn_w = (const float*)d_in[19];
    const float* dbn_b = (const float*)d_in[20];
    float* out = (float*)d_out;
    u16*   wsu = (u16*)d_ws;
    float* wsf = (float*)d_ws;

    u16* a2f  = wsu + WS_A2F_U;
    u16* xq   = wsu + WS_XQ_U;
    u16* xd   = wsu + WS_XD_U;
    u16* yb   = wsu + WS_YB_U;
    float* xm    = wsf + WS_XM_F;
    float* rs    = wsf + WS_RS_F;
    float* stats = wsf + WS_STAT_F;
    float* coef  = wsf + WS_COEF_F;

    // zero rs_tot + stats (contiguous) — accumulated via atomics each call
    hipMemsetAsync(rs, 0, (N_ * O_ * V_ + 4 * O_) * sizeof(float), stream);

    k0_xq<<<N_ * 128, 256, 0, stream>>>(x, xq);
    k1_xm<<<N_ * 25, 256, 0, stream>>>(xq, xm);
    k2_a2f<<<N_ * S_ * 8, 256, 0, stream>>>(spd, A3, A6, w1, b1, w2, b2, w4, b4, b3,
                                            alpha, beta, gamma, a2f, xm, rs);
    k3_main<<<N_ * 24, 256, 0, stream>>>(xq, w3, dw, db, a2f, rs, yb, xd, stats);
    k4_coef<<<1, 256, 0, stream>>>(bn_w, bn_b, dbn_w, dbn_b, stats, coef);
    k5_final<<<4096, 256, 0, stream>>>(out, yb, xd, coef);
}

// Round 16
// 311.346 us; speedup vs baseline: 1.4548x; 1.0880x over previous
//
#include <hip/hip_runtime.h>

#define N_ 32
#define C_ 64
#define T_ 256
#define V_ 25
#define O_ 192
#define S_ 3
#define R_ 8
#define VV (V_*V_)      // 625
#define TV (T_*V_)      // 6400
#define RP 26           // padded v-rows per t
#define TRP (T_*RP)     // 6656 rows per n

typedef unsigned short u16;
typedef unsigned int u32;
typedef __attribute__((ext_vector_type(4))) u16 u16x4;
typedef __attribute__((ext_vector_type(8))) u16 u16x8;
typedef __attribute__((ext_vector_type(4))) u32 u32x4;
typedef __attribute__((ext_vector_type(8))) __bf16 bf16x8;
typedef __attribute__((ext_vector_type(4))) float f32x4;

// ---- workspace layout (u16 units) ----
#define WS_A2F_U 0                                   // N*O*6*64*8 = 18,874,368
#define WS_XQ_U  (18874368)                          // 13,631,488
#define WS_XD_U  (18874368 + 13631488)               // 39,321,600
#define WS_YB_U  (18874368 + 13631488 + 39321600)    // 39,321,600 (y as bf16)
// float region (after 111,149,056 u16):
#define WS_XM_F   (55574528)                         // N*C*V = 51,200
#define WS_RS_F   (55574528 + 51200)                 // N*O*V = 153,600
#define WS_STAT_F (55574528 + 51200 + 153600)        // 4*O
#define WS_COEF_F (55574528 + 51200 + 153600 + 768)  // 4*O

__device__ __forceinline__ u16 f2b(float f) {
    return __builtin_bit_cast(u16, (__bf16)f);
}
__device__ __forceinline__ float b2f(u16 u) {
    return __builtin_bit_cast(float, ((unsigned)u) << 16);
}
__device__ __forceinline__ f32x4 mfma16(bf16x8 a, bf16x8 b, f32x4 c) {
    return __builtin_amdgcn_mfma_f32_16x16x32_bf16(a, b, c, 0, 0, 0);
}

// ---------------- K0: x[n,c,t,v] fp32 -> xq[n][t*26+v][c' perm] bf16 ----------------
__global__ void k0_xq(const float* __restrict__ x, u16* __restrict__ xq) {
    __shared__ float tile[64][52];
    int bid = blockIdx.x;
    int n = bid >> 7, tb = bid & 127;
    int t0 = tb * 2;
    int tid = threadIdx.x;
    const float2* xp = (const float2*)(x + (size_t)n * C_ * TV + t0 * 25);
    for (int p = tid; p < 1600; p += 256) {
        int c = p / 25, q = p % 25;
        float2 f2 = xp[(size_t)c * 3200 + q];
        tile[c][q * 2] = f2.x;
        tile[c][q * 2 + 1] = f2.y;
    }
    __syncthreads();
    for (int p = tid; p < 832; p += 256) {
        int row = p >> 4, c4g = p & 15;
        int t = row >= RP, v = row - t * RP;
        u16x4 w;
        #pragma unroll
        for (int i = 0; i < 4; ++i) {
            int co = ((c4g & 3) << 4) + ((c4g >> 2) << 2) + i;
            w[i] = (v < 25) ? f2b(tile[co][t * 25 + v]) : (u16)0;
        }
        *(u16x4*)&xq[((size_t)n * TRP + tb * 52 + row) * 64 + c4g * 4] = w;
    }
}

// ---------------- K1: xm[n,c,v] from xq (bf16, 26 MB) ----------------
__global__ void k1_xm(const u16* __restrict__ xq, float* __restrict__ xm_out) {
    __shared__ float ps[256];
    int bid = blockIdx.x;
    int n = bid / 25, v = bid % 25;
    int tid = threadIdx.x;
    int cg = tid & 63, tg = tid >> 6;
    const u16* p = xq + (size_t)n * TRP * 64 + ((size_t)(tg * 64 * RP + v)) * 64 + cg;
    float s = 0.f;
    for (int t = 0; t < 64; ++t) {
        s += b2f(*p);
        p += RP * 64;
    }
    ps[tid] = s;
    __syncthreads();
    if (tid < 64) {
        float tot = ps[tid] + ps[64 + tid] + ps[128 + tid] + ps[192 + tid];
        int c4g = tid >> 2, i = tid & 3;
        int co = ((c4g & 3) << 4) + ((c4g >> 2) << 2) + i;
        xm_out[((size_t)n * C_ + co) * V_ + v] = tot * (1.f / T_);
    }
}

// ---------------- K2: barrier-free per-wave A2F build + rs_tot (R14 version) ----------------
__global__ void k2_a2f(const float* __restrict__ spd, const float* __restrict__ A3,
                       const float* __restrict__ A6,
                       const float* __restrict__ w1, const float* __restrict__ b1,
                       const float* __restrict__ w2, const float* __restrict__ b2,
                       const float* __restrict__ w4, const float* __restrict__ b4,
                       const float* __restrict__ b3,
                       const float* __restrict__ alpha, const float* __restrict__ beta,
                       const float* __restrict__ gamma,
                       u16* __restrict__ a2f, const float* __restrict__ xmbuf,
                       float* __restrict__ rs_tot) {
    __shared__ float xm[C_ * V_];
    __shared__ float x1s[R_ * V_], x2s[R_ * V_];
    __shared__ float dm[R_ * VV];
    __shared__ float a3s[VV], sps[VV];
    __shared__ float aatw[4][2 * VV];
    int bid = blockIdx.x;
    int n = bid / 24;
    int rem = bid % 24;
    int s = rem / 8, og = rem % 8;
    int tid = threadIdx.x, wid = tid >> 6, lane = tid & 63;
    const float* xmg = xmbuf + (size_t)n * C_ * V_;
    for (int p = tid; p < C_ * V_; p += 256) xm[p] = xmg[p];
    for (int p = tid; p < VV; p += 256) { a3s[p] = A3[s * VV + p]; sps[p] = spd[p]; }
    __syncthreads();
    if (tid < R_ * V_) {
        int r = tid / V_, v = tid % V_;
        float acc1 = b1[s * R_ + r], acc2 = b2[s * R_ + r];
        for (int c = 0; c < C_; ++c) {
            float xv = xm[c * V_ + v];
            acc1 += xv * w1[(s * R_ + r) * C_ + c];
            acc2 += xv * w2[(s * R_ + r) * C_ + c];
        }
        x1s[tid] = acc1; x2s[tid] = acc2;
    }
    __syncthreads();
    for (int p = tid; p < R_ * VV; p += 256) {
        int r = p / VV, uv = p % VV, u = uv / V_, v = uv % V_;
        dm[p] = tanhf(x1s[r * V_ + u] - x2s[r * V_ + v]);
    }
    __syncthreads();
    float al = alpha[0], be = beta[0], ga = gamma[0];
    float* aat = aatw[wid];
    for (int opi = 0; opi < 3; ++opi) {
        int op = wid * 3 + opi;
        int o0 = og * 24 + op * 2;
        float w4v[2][R_], b4v[2];
        #pragma unroll
        for (int oo = 0; oo < 2; ++oo) {
            b4v[oo] = b4[s * O_ + o0 + oo];
            #pragma unroll
            for (int r = 0; r < R_; ++r)
                w4v[oo][r] = w4[((size_t)(s * O_ + o0 + oo)) * R_ + r];
        }
        const float* a6p0 = A6 + ((o0 % 6) * VV);
        for (int p = lane; p < 2 * VV; p += 64) {
            int oo = p / VV, pp = p - oo * VV;
            float acc = b4v[oo];
            #pragma unroll
            for (int r = 0; r < R_; ++r) acc += dm[r * VV + pp] * w4v[oo][r];
            aat[p] = al * acc + a3s[pp] + ga * sps[pp] + be * a6p0[oo * VV + pp];
        }
        if (lane < 2 * V_) {
            int oo = lane / V_, u = lane - oo * V_;
            float rs = 0.f;
            for (int v = 0; v < V_; ++v) rs += aat[oo * VV + u * V_ + v];
            atomicAdd(&rs_tot[((size_t)(n * O_ + o0 + oo)) * V_ + u],
                      b3[s * O_ + o0 + oo] * rs);
        }
        #pragma unroll
        for (int it = 0; it < 4; ++it) {
            int idx = it * 64 + lane;
            int oo = idx >> 7, l2 = idx & 127, cu = l2 >> 6, l = l2 & 63;
            int u = cu * 16 + (l & 15);
            u16x8 w;
            #pragma unroll
            for (int j = 0; j < 8; ++j) {
                int v = ((j >> 2) << 4) + ((l >> 4) << 2) + (j & 3);
                float val = 0.f;
                if (u < V_ && v < V_) val = aat[oo * VV + u * V_ + v];
                w[j] = f2b(val);
            }
            size_t idxg = ((((size_t)(n * O_ + o0 + oo)) * S_ + s) * 2 + cu) * 64 + l;
            ((u16x8*)a2f)[idxg] = w;
        }
    }
}

// ---------------- K3: R13 champion (768-block convoy, dbuf, depth-4 prefetch) ----------------
#define OSTR_B 2504          // /4 = 626 ≡ 18 (mod 32)
#define SSTR_B 832           // 416 rows * 2B
#define BUF_B  20064         // 8*2504 + 32 pad

__global__ __launch_bounds__(256, 3)
void k3_main(const u16* __restrict__ xq,
             const float* __restrict__ w3, const float* __restrict__ dw,
             const float* __restrict__ db,
             const u16* __restrict__ a2f, const float* __restrict__ rs_tot,
             u16* __restrict__ yb16, u16* __restrict__ xdws,
             float* __restrict__ stats) {
    __shared__ char x3Lb[2 * BUF_B];    // 40,128 B
    __shared__ u16 xdst[8 * 416];       //  6,656 B
    __shared__ u16 ystage[8 * 400];     //  6,400 B
    int orig = blockIdx.x;
    int bid = (orig & 7) * 96 + (orig >> 3);   // same-n blocks -> same XCD
    int n = bid / 24;
    int o0 = (bid % 24) * 8;
    int tid = threadIdx.x, wid = tid >> 6, lane = tid & 63;
    int lr = lane & 15, lg = lane >> 4;
    int colt = wid & 1;
    int rt0 = (wid >> 1) * 13;

    for (int p = tid; p < 2 * BUF_B / 16; p += 256) ((u32x4*)x3Lb)[p] = u32x4{0,0,0,0};

    const float* wsrc = (colt == 0)
        ? w3 + ((size_t)((lr >> 3) * O_ + o0 + (lr & 7))) * C_
        : ((lr < 8) ? w3 + ((size_t)(2 * O_ + o0 + lr)) * C_
                    : dw + ((size_t)(o0 + lr - 8)) * C_);
    bf16x8 bw[2];
    #pragma unroll
    for (int ks = 0; ks < 2; ++ks) {
        u16x8 tmp;
        #pragma unroll
        for (int j = 0; j < 8; ++j) {
            int c = ks * 32 + (lg << 2) + (j & 3) + ((j >> 2) << 4);
            tmp[j] = f2b(wsrc[c]);
        }
        bw[ks] = __builtin_bit_cast(bf16x8, tmp);
    }
    float dbv = (colt == 1 && lr >= 8) ? db[o0 + lr - 8] : 0.f;

    int wo = (colt == 0) ? (lr & 7) : lr;
    int wsb = (colt == 0) ? (lr >> 3) : 2;
    int colbyte = wo * OSTR_B + wsb * SSTR_B;

    const bf16x8* a2v = (const bf16x8*)a2f;
    bf16x8 Bh[2][6];
    float rsb0[2], rsb1[2];
    #pragma unroll
    for (int oi = 0; oi < 2; ++oi) {
        int o = o0 + (wid << 1) + oi;
        const bf16x8* bp = a2v + ((size_t)(n * O_ + o)) * 6 * 64 + lane;
        #pragma unroll
        for (int q = 0; q < 6; ++q) Bh[oi][q] = bp[(size_t)q * 64];
        const float* rsp = rs_tot + ((size_t)(n * O_ + o)) * V_;
        rsb0[oi] = rsp[lr];
        rsb1[oi] = (lr < 9) ? rsp[16 + lr] : 0.f;
    }

    float sy1[2] = {0, 0}, sy2[2] = {0, 0};
    float sd1 = 0.f, sd2 = 0.f;
    const u16* xbn = xq + (size_t)n * TRP * 64;
    int rdw = 13 * lr + 2 * lg;
    char* buf = x3Lb;
    int t0 = 0;

    auto tl = [&](int ch, int j, u16x8& A0, u16x8& A1) {
        const u16* p = xbn + ((size_t)(ch * 16) * RP + (size_t)((rt0 + j) * 16 + lr)) * 64
                       + (lg << 4);
        A0 = *(const u16x8*)p;
        A1 = *(const u16x8*)(p + 8);
    };
    auto proc = [&](int rt, u16x8 A0, u16x8 A1) {
        f32x4 acc = {0.f, 0.f, 0.f, 0.f};
        acc = mfma16(__builtin_bit_cast(bf16x8, A0), bw[0], acc);
        acc = mfma16(__builtin_bit_cast(bf16x8, A1), bw[1], acc);
        int rbase = rt * 16 + (lg << 2);
        if (colt == 0 || lr < 8) {
            u16x4 w;
            #pragma unroll
            for (int reg = 0; reg < 4; ++reg) w[reg] = f2b(acc[reg]);
            *(u16x4*)(buf + colbyte + rbase * 2) = w;
        } else {
            u16x4 w;
            #pragma unroll
            for (int reg = 0; reg < 4; ++reg) {
                int rr = rbase + reg;
                int t = rr / RP, v = rr - t * RP;
                float val = acc[reg] + dbv;
                w[reg] = f2b(val);
                if (v < 25) { sd1 += val; sd2 += val * val; }
            }
            *(u16x4*)&xdst[(lr - 8) * 416 + rbase] = w;
        }
    };

    __syncthreads();                           // init fence

    u16x8 p0a, p0b, p1a, p1b, p2a, p2b, p3a, p3b;
    tl(0, 0, p0a, p0b); tl(0, 1, p1a, p1b); tl(0, 2, p2a, p2b); tl(0, 3, p3a, p3b);

    for (int ch = 0; ch < 16; ++ch) {
        t0 = ch * 16;
        buf = x3Lb + (ch & 1) * BUF_B;
        // ---- GEMM1: peeled prefetched tiles 0..3, then in-chunk 4..12
        proc(rt0 + 0, p0a, p0b);
        proc(rt0 + 1, p1a, p1b);
        proc(rt0 + 2, p2a, p2b);
        proc(rt0 + 3, p3a, p3b);
        for (int j = 4; j < 13; ++j) {
            u16x8 A0, A1;
            tl(ch, j, A0, A1);
            proc(rt0 + j, A0, A1);
        }
        // prefetch next chunk's tiles 0..3 (in flight across barrier + GEMM2)
        if (ch < 15) {
            tl(ch + 1, 0, p0a, p0b); tl(ch + 1, 1, p1a, p1b);
            tl(ch + 1, 2, p2a, p2b); tl(ch + 1, 3, p3a, p3b);
        }
        __syncthreads();   // x3/xdst handoff; dbuf covers write-after-read
        // ---- GEMM2 -> ystage (bf16)
        #pragma unroll
        for (int oi = 0; oi < 2; ++oi) {
            int ol = (wid << 1) + oi;
            const u32* L = (const u32*)(buf + ol * OSTR_B);
            f32x4 acc0 = {0, 0, 0, 0}, acc1 = {0, 0, 0, 0};
            #pragma unroll
            for (int s = 0; s < 3; ++s) {
                const u32* Ls = L + s * 208 + rdw;
                u32 d0 = Ls[0], d1 = Ls[1], d8 = Ls[8], d9 = Ls[9];
                bf16x8 A = __builtin_bit_cast(bf16x8, u32x4{d0, d1, d8, d9});
                acc0 = mfma16(A, Bh[oi][s * 2 + 0], acc0);
                acc1 = mfma16(A, Bh[oi][s * 2 + 1], acc1);
            }
            int ylb = ol * 400 + (lg << 2) * 25;
            #pragma unroll
            for (int reg = 0; reg < 4; ++reg) {
                float v0 = acc0[reg] + rsb0[oi];
                ystage[ylb + reg * 25 + lr] = f2b(v0);
                sy1[oi] += v0; sy2[oi] += v0 * v0;
                if (lr < 9) {
                    float v1 = acc1[reg] + rsb1[oi];
                    ystage[ylb + reg * 25 + 16 + lr] = f2b(v1);
                    sy1[oi] += v1; sy2[oi] += v1 * v1;
                }
            }
        }
        // ---- per-wave y compaction: coalesced 16B stores of own 2 o's
        {
            size_t ygb = (size_t)(n * O_ + o0) * TV + (size_t)t0 * V_;
            for (int q = lane; q < 100; q += 64) {
                int sel = q >= 50;
                int ol2 = (wid << 1) + sel;
                int j = q - sel * 50;
                u16x8 pk = *(const u16x8*)&ystage[ol2 * 400 + j * 8];
                *(u16x8*)&yb16[ygb + (size_t)ol2 * TV + j * 8] = pk;
            }
        }
        // ---- per-wave xd compaction (colt1 waves own their staged halves)
        if (colt == 1) {
            int tofs = (wid >> 1) * 8;
            size_t gdb = (size_t)(n * O_ + o0) * TV + (size_t)(t0 + tofs) * V_;
            for (int q = lane; q < 200; q += 64) {
                int o = q / 25, w = q - o * 25;
                int g0 = w * 8;
                int tl2 = g0 / 25, v = g0 - tl2 * 25;
                u16x8 pk;
                #pragma unroll
                for (int k = 0; k < 8; ++k) {
                    pk[k] = xdst[o * 416 + (tofs + tl2) * RP + v];
                    if (++v == 25) { v = 0; ++tl2; }
                }
                *(u16x8*)&xdws[gdb + (size_t)o * TV + g0] = pk;
            }
        }
    }
    // stats -> global atomics
    #pragma unroll
    for (int oi = 0; oi < 2; ++oi) {
        float v1 = sy1[oi], v2 = sy2[oi];
        #pragma unroll
        for (int m = 1; m < 64; m <<= 1) {
            v1 += __shfl_xor(v1, m);
            v2 += __shfl_xor(v2, m);
        }
        if (lane == 0) {
            atomicAdd(&stats[0 * O_ + o0 + (wid << 1) + oi], v1);
            atomicAdd(&stats[1 * O_ + o0 + (wid << 1) + oi], v2);
        }
    }
    if (colt == 1) {
        float v1 = sd1, v2 = sd2;
        v1 += __shfl_xor(v1, 16); v2 += __shfl_xor(v2, 16);
        v1 += __shfl_xor(v1, 32); v2 += __shfl_xor(v2, 32);
        if (lane >= 8 && lane < 16) {
            atomicAdd(&stats[2 * O_ + o0 + lane - 8], v1);
            atomicAdd(&stats[3 * O_ + o0 + lane - 8], v2);
        }
    }
}

// ---------------- K4: BN coefficients ----------------
__global__ void k4_coef(const float* __restrict__ bn_w, const float* __restrict__ bn_b,
                        const float* __restrict__ dbn_w, const float* __restrict__ dbn_b,
                        const float* __restrict__ stats, float* __restrict__ coef) {
    int o = threadIdx.x;
    if (o >= O_) return;
    float inv = 1.f / (float)(N_ * T_ * V_);
    float mu_y = stats[o] * inv;
    float var_y = stats[O_ + o] * inv - mu_y * mu_y;
    float ay = bn_w[o] * rsqrtf(var_y + 1e-5f);
    float by = bn_b[o] - mu_y * ay;
    float mu_d = stats[2 * O_ + o] * inv;
    float var_d = stats[3 * O_ + o] * inv - mu_d * mu_d;
    float ad = dbn_w[o] * rsqrtf(var_d + 1e-5f);
    float bd = dbn_b[o] - mu_d * ad;
    coef[o] = ay; coef[O_ + o] = by; coef[2 * O_ + o] = ad; coef[3 * O_ + o] = bd;
}

// ---------------- K5: final BN+residual+relu (y bf16 + xd bf16 -> out fp32) ----------------
__global__ void k5_final(float* __restrict__ out, const u16* __restrict__ yb,
                         const u16* __restrict__ xd, const float* __restrict__ cf) {
    size_t total = (size_t)N_ * O_ * TV / 8;
    for (size_t i = blockIdx.x * (size_t)blockDim.x + threadIdx.x; i < total;
         i += (size_t)gridDim.x * blockDim.x) {
        int o = (int)((i / 800) % O_);
        float ay = cf[o], by = cf[O_ + o], ad = cf[2 * O_ + o], bd = cf[3 * O_ + o];
        u16x8 yv = ((const u16x8*)yb)[i];
        u16x8 dv = ((const u16x8*)xd)[i];
        float4 r0, r1;
        r0.x = fmaxf(ay * b2f(yv[0]) + by + ad * b2f(dv[0]) + bd, 0.f);
        r0.y = fmaxf(ay * b2f(yv[1]) + by + ad * b2f(dv[1]) + bd, 0.f);
        r0.z = fmaxf(ay * b2f(yv[2]) + by + ad * b2f(dv[2]) + bd, 0.f);
        r0.w = fmaxf(ay * b2f(yv[3]) + by + ad * b2f(dv[3]) + bd, 0.f);
        r1.x = fmaxf(ay * b2f(yv[4]) + by + ad * b2f(dv[4]) + bd, 0.f);
        r1.y = fmaxf(ay * b2f(yv[5]) + by + ad * b2f(dv[5]) + bd, 0.f);
        r1.z = fmaxf(ay * b2f(yv[6]) + by + ad * b2f(dv[6]) + bd, 0.f);
        r1.w = fmaxf(ay * b2f(yv[7]) + by + ad * b2f(dv[7]) + bd, 0.f);
        ((float4*)out)[2 * i] = r0;
        ((float4*)out)[2 * i + 1] = r1;
    }
}

extern "C" void kernel_launch(void* const* d_in, const int* in_sizes, int n_in,
                              void* d_out, int out_size, void* d_ws, size_t ws_size,
                              hipStream_t stream) {
    const float* x     = (const float*)d_in[0];
    const float* spd   = (const float*)d_in[1];
    const float* A3    = (const float*)d_in[2];
    const float* A6    = (const float*)d_in[3];
    const float* w1    = (const float*)d_in[4];
    const float* b1    = (const float*)d_in[5];
    const float* w2    = (const float*)d_in[6];
    const float* b2    = (const float*)d_in[7];
    const float* w4    = (const float*)d_in[8];
    const float* b4    = (const float*)d_in[9];
    const float* w3    = (const float*)d_in[10];
    const float* b3    = (const float*)d_in[11];
    const float* alpha = (const float*)d_in[12];
    const float* beta  = (const float*)d_in[13];
    const float* gamma = (const float*)d_in[14];
    const float* bn_w  = (const float*)d_in[15];
    const float* bn_b  = (const float*)d_in[16];
    const float* dw    = (const float*)d_in[17];
    const float* db    = (const float*)d_in[18];
    const float* dbn_w = (const float*)d_in[19];
    const float* dbn_b = (const float*)d_in[20];
    float* out = (float*)d_out;
    u16*   wsu = (u16*)d_ws;
    float* wsf = (float*)d_ws;

    u16* a2f  = wsu + WS_A2F_U;
    u16* xq   = wsu + WS_XQ_U;
    u16* xd   = wsu + WS_XD_U;
    u16* yb   = wsu + WS_YB_U;
    float* xm    = wsf + WS_XM_F;
    float* rs    = wsf + WS_RS_F;
    float* stats = wsf + WS_STAT_F;
    float* coef  = wsf + WS_COEF_F;

    // zero rs_tot + stats (contiguous) — accumulated via atomics each call
    hipMemsetAsync(rs, 0, (N_ * O_ * V_ + 4 * O_) * sizeof(float), stream);

    k0_xq<<<N_ * 128, 256, 0, stream>>>(x, xq);
    k1_xm<<<N_ * 25, 256, 0, stream>>>(xq, xm);
    k2_a2f<<<N_ * S_ * 8, 256, 0, stream>>>(spd, A3, A6, w1, b1, w2, b2, w4, b4, b3,
                                            alpha, beta, gamma, a2f, xm, rs);
    k3_main<<<N_ * 24, 256, 0, stream>>>(xq, w3, dw, db, a2f, rs, yb, xd, stats);
    k4_coef<<<1, 256, 0, stream>>>(bn_w, bn_b, dbn_w, dbn_b, stats, coef);
    k5_final<<<4096, 256, 0, stream>>>(out, yb, xd, coef);
}

// Round 17
// 311.229 us; speedup vs baseline: 1.4553x; 1.0004x over previous
//
#include <hip/hip_runtime.h>

#define N_ 32
#define C_ 64
#define T_ 256
#define V_ 25
#define O_ 192
#define S_ 3
#define R_ 8
#define VV (V_*V_)      // 625
#define TV (T_*V_)      // 6400
#define RP 26           // padded v-rows per t
#define TRP (T_*RP)     // 6656 rows per n

typedef unsigned short u16;
typedef unsigned int u32;
typedef __attribute__((ext_vector_type(4))) u16 u16x4;
typedef __attribute__((ext_vector_type(8))) u16 u16x8;
typedef __attribute__((ext_vector_type(4))) u32 u32x4;
typedef __attribute__((ext_vector_type(8))) __bf16 bf16x8;
typedef __attribute__((ext_vector_type(4))) float f32x4;

// ---- workspace layout (u16 units) ----
#define WS_A2F_U 0                                   // N*O*6*64*8 = 18,874,368
#define WS_XQ_U  (18874368)                          // 13,631,488
#define WS_XD_U  (18874368 + 13631488)               // 39,321,600
#define WS_YB_U  (18874368 + 13631488 + 39321600)    // 39,321,600 (y as bf16)
// float region (after 111,149,056 u16):
#define WS_XM_F   (55574528)                         // N*C*V = 51,200
#define WS_RS_F   (55574528 + 51200)                 // N*O*V = 153,600
#define WS_STAT_F (55574528 + 51200 + 153600)        // 4*O
#define WS_COEF_F (55574528 + 51200 + 153600 + 768)  // 4*O

__device__ __forceinline__ u16 f2b(float f) {
    return __builtin_bit_cast(u16, (__bf16)f);
}
__device__ __forceinline__ float b2f(u16 u) {
    return __builtin_bit_cast(float, ((unsigned)u) << 16);
}
__device__ __forceinline__ f32x4 mfma16(bf16x8 a, bf16x8 b, f32x4 c) {
    return __builtin_amdgcn_mfma_f32_16x16x32_bf16(a, b, c, 0, 0, 0);
}

// ---------------- K0: x[n,c,t,v] fp32 -> xq[n][t*26+v][c' perm] bf16 ----------------
__global__ void k0_xq(const float* __restrict__ x, u16* __restrict__ xq) {
    __shared__ float tile[64][52];
    int bid = blockIdx.x;
    int n = bid >> 7, tb = bid & 127;
    int t0 = tb * 2;
    int tid = threadIdx.x;
    const float2* xp = (const float2*)(x + (size_t)n * C_ * TV + t0 * 25);
    for (int p = tid; p < 1600; p += 256) {
        int c = p / 25, q = p % 25;
        float2 f2 = xp[(size_t)c * 3200 + q];
        tile[c][q * 2] = f2.x;
        tile[c][q * 2 + 1] = f2.y;
    }
    __syncthreads();
    for (int p = tid; p < 832; p += 256) {
        int row = p >> 4, c4g = p & 15;
        int t = row >= RP, v = row - t * RP;
        u16x4 w;
        #pragma unroll
        for (int i = 0; i < 4; ++i) {
            int co = ((c4g & 3) << 4) + ((c4g >> 2) << 2) + i;
            w[i] = (v < 25) ? f2b(tile[co][t * 25 + v]) : (u16)0;
        }
        *(u16x4*)&xq[((size_t)n * TRP + tb * 52 + row) * 64 + c4g * 4] = w;
    }
}

// ---------------- K1: xm[n,c,v] from xq (bf16, 26 MB) ----------------
__global__ void k1_xm(const u16* __restrict__ xq, float* __restrict__ xm_out) {
    __shared__ float ps[256];
    int bid = blockIdx.x;
    int n = bid / 25, v = bid % 25;
    int tid = threadIdx.x;
    int cg = tid & 63, tg = tid >> 6;
    const u16* p = xq + (size_t)n * TRP * 64 + ((size_t)(tg * 64 * RP + v)) * 64 + cg;
    float s = 0.f;
    for (int t = 0; t < 64; ++t) {
        s += b2f(*p);
        p += RP * 64;
    }
    ps[tid] = s;
    __syncthreads();
    if (tid < 64) {
        float tot = ps[tid] + ps[64 + tid] + ps[128 + tid] + ps[192 + tid];
        int c4g = tid >> 2, i = tid & 3;
        int co = ((c4g & 3) << 4) + ((c4g >> 2) << 2) + i;
        xm_out[((size_t)n * C_ + co) * V_ + v] = tot * (1.f / T_);
    }
}

// ---------------- K2: barrier-free per-wave A2F build + rs_tot ----------------
__global__ void k2_a2f(const float* __restrict__ spd, const float* __restrict__ A3,
                       const float* __restrict__ A6,
                       const float* __restrict__ w1, const float* __restrict__ b1,
                       const float* __restrict__ w2, const float* __restrict__ b2,
                       const float* __restrict__ w4, const float* __restrict__ b4,
                       const float* __restrict__ b3,
                       const float* __restrict__ alpha, const float* __restrict__ beta,
                       const float* __restrict__ gamma,
                       u16* __restrict__ a2f, const float* __restrict__ xmbuf,
                       float* __restrict__ rs_tot) {
    __shared__ float xm[C_ * V_];
    __shared__ float x1s[R_ * V_], x2s[R_ * V_];
    __shared__ float dm[R_ * VV];
    __shared__ float a3s[VV], sps[VV];
    __shared__ float aatw[4][2 * VV];
    int bid = blockIdx.x;
    int n = bid / 24;
    int rem = bid % 24;
    int s = rem / 8, og = rem % 8;
    int tid = threadIdx.x, wid = tid >> 6, lane = tid & 63;
    const float* xmg = xmbuf + (size_t)n * C_ * V_;
    for (int p = tid; p < C_ * V_; p += 256) xm[p] = xmg[p];
    for (int p = tid; p < VV; p += 256) { a3s[p] = A3[s * VV + p]; sps[p] = spd[p]; }
    __syncthreads();
    if (tid < R_ * V_) {
        int r = tid / V_, v = tid % V_;
        float acc1 = b1[s * R_ + r], acc2 = b2[s * R_ + r];
        for (int c = 0; c < C_; ++c) {
            float xv = xm[c * V_ + v];
            acc1 += xv * w1[(s * R_ + r) * C_ + c];
            acc2 += xv * w2[(s * R_ + r) * C_ + c];
        }
        x1s[tid] = acc1; x2s[tid] = acc2;
    }
    __syncthreads();
    for (int p = tid; p < R_ * VV; p += 256) {
        int r = p / VV, uv = p % VV, u = uv / V_, v = uv % V_;
        dm[p] = tanhf(x1s[r * V_ + u] - x2s[r * V_ + v]);
    }
    __syncthreads();
    float al = alpha[0], be = beta[0], ga = gamma[0];
    float* aat = aatw[wid];
    for (int opi = 0; opi < 3; ++opi) {
        int op = wid * 3 + opi;
        int o0 = og * 24 + op * 2;
        float w4v[2][R_], b4v[2];
        #pragma unroll
        for (int oo = 0; oo < 2; ++oo) {
            b4v[oo] = b4[s * O_ + o0 + oo];
            #pragma unroll
            for (int r = 0; r < R_; ++r)
                w4v[oo][r] = w4[((size_t)(s * O_ + o0 + oo)) * R_ + r];
        }
        const float* a6p0 = A6 + ((o0 % 6) * VV);
        for (int p = lane; p < 2 * VV; p += 64) {
            int oo = p / VV, pp = p - oo * VV;
            float acc = b4v[oo];
            #pragma unroll
            for (int r = 0; r < R_; ++r) acc += dm[r * VV + pp] * w4v[oo][r];
            aat[p] = al * acc + a3s[pp] + ga * sps[pp] + be * a6p0[oo * VV + pp];
        }
        if (lane < 2 * V_) {
            int oo = lane / V_, u = lane - oo * V_;
            float rs = 0.f;
            for (int v = 0; v < V_; ++v) rs += aat[oo * VV + u * V_ + v];
            atomicAdd(&rs_tot[((size_t)(n * O_ + o0 + oo)) * V_ + u],
                      b3[s * O_ + o0 + oo] * rs);
        }
        #pragma unroll
        for (int it = 0; it < 4; ++it) {
            int idx = it * 64 + lane;
            int oo = idx >> 7, l2 = idx & 127, cu = l2 >> 6, l = l2 & 63;
            int u = cu * 16 + (l & 15);
            u16x8 w;
            #pragma unroll
            for (int j = 0; j < 8; ++j) {
                int v = ((j >> 2) << 4) + ((l >> 4) << 2) + (j & 3);
                float val = 0.f;
                if (u < V_ && v < V_) val = aat[oo * VV + u * V_ + v];
                w[j] = f2b(val);
            }
            size_t idxg = ((((size_t)(n * O_ + o0 + oo)) * S_ + s) * 2 + cu) * 64 + l;
            ((u16x8*)a2f)[idxg] = w;
        }
    }
}

// ---------------- K3: rotated pipeline — GEMM1(ch+1) overlaps GEMM2(ch);
// raw s_barrier with lgkmcnt-only wait (loads stay in flight across barriers).
#define OSTR_B 2504          // /4 = 626 ≡ 18 (mod 32)
#define SSTR_B 832           // 416 rows * 2B
#define BUF_B  20064         // 8*2504 + 32 pad

__global__ __launch_bounds__(256, 3)
void k3_main(const u16* __restrict__ xq,
             const float* __restrict__ w3, const float* __restrict__ dw,
             const float* __restrict__ db,
             const u16* __restrict__ a2f, const float* __restrict__ rs_tot,
             u16* __restrict__ yb16, u16* __restrict__ xdws,
             float* __restrict__ stats) {
    __shared__ char x3Lb[2 * BUF_B];    // 40,128 B
    __shared__ u16 xdst[8 * 416];       //  6,656 B
    __shared__ u16 ystage[8 * 400];     //  6,400 B
    int orig = blockIdx.x;
    int bid = (orig & 7) * 96 + (orig >> 3);   // same-n blocks -> same XCD
    int n = bid / 24;
    int o0 = (bid % 24) * 8;
    int tid = threadIdx.x, wid = tid >> 6, lane = tid & 63;
    int lr = lane & 15, lg = lane >> 4;
    int colt = wid & 1;
    int rt0 = (wid >> 1) * 13;

    for (int p = tid; p < 2 * BUF_B / 16; p += 256) ((u32x4*)x3Lb)[p] = u32x4{0,0,0,0};

    const float* wsrc = (colt == 0)
        ? w3 + ((size_t)((lr >> 3) * O_ + o0 + (lr & 7))) * C_
        : ((lr < 8) ? w3 + ((size_t)(2 * O_ + o0 + lr)) * C_
                    : dw + ((size_t)(o0 + lr - 8)) * C_);
    bf16x8 bw[2];
    #pragma unroll
    for (int ks = 0; ks < 2; ++ks) {
        u16x8 tmp;
        #pragma unroll
        for (int j = 0; j < 8; ++j) {
            int c = ks * 32 + (lg << 2) + (j & 3) + ((j >> 2) << 4);
            tmp[j] = f2b(wsrc[c]);
        }
        bw[ks] = __builtin_bit_cast(bf16x8, tmp);
    }
    float dbv = (colt == 1 && lr >= 8) ? db[o0 + lr - 8] : 0.f;

    int wo = (colt == 0) ? (lr & 7) : lr;
    int wsb = (colt == 0) ? (lr >> 3) : 2;
    int colbyte = wo * OSTR_B + wsb * SSTR_B;

    const bf16x8* a2v = (const bf16x8*)a2f;
    bf16x8 Bh[2][6];
    float rsb0[2], rsb1[2];
    #pragma unroll
    for (int oi = 0; oi < 2; ++oi) {
        int o = o0 + (wid << 1) + oi;
        const bf16x8* bp = a2v + ((size_t)(n * O_ + o)) * 6 * 64 + lane;
        #pragma unroll
        for (int q = 0; q < 6; ++q) Bh[oi][q] = bp[(size_t)q * 64];
        const float* rsp = rs_tot + ((size_t)(n * O_ + o)) * V_;
        rsb0[oi] = rsp[lr];
        rsb1[oi] = (lr < 9) ? rsp[16 + lr] : 0.f;
    }

    float sy1[2] = {0, 0}, sy2[2] = {0, 0};
    float sd1 = 0.f, sd2 = 0.f;
    const u16* xbn = xq + (size_t)n * TRP * 64;
    int rdw = 13 * lr + 2 * lg;

    // GEMM1 for chunk ch: 13 row-tiles -> buf(ch&1) (+ xdst for down column)
    auto g1 = [&](int ch) {
        char* bufw = x3Lb + (ch & 1) * BUF_B;
        for (int j = 0; j < 13; ++j) {
            const u16* p = xbn + ((size_t)(ch * 16) * RP
                                  + (size_t)((rt0 + j) * 16 + lr)) * 64 + (lg << 4);
            u16x8 A0 = *(const u16x8*)p;
            u16x8 A1 = *(const u16x8*)(p + 8);
            f32x4 acc = {0.f, 0.f, 0.f, 0.f};
            acc = mfma16(__builtin_bit_cast(bf16x8, A0), bw[0], acc);
            acc = mfma16(__builtin_bit_cast(bf16x8, A1), bw[1], acc);
            int rbase = (rt0 + j) * 16 + (lg << 2);
            if (colt == 0 || lr < 8) {
                u16x4 w;
                #pragma unroll
                for (int reg = 0; reg < 4; ++reg) w[reg] = f2b(acc[reg]);
                *(u16x4*)(bufw + colbyte + rbase * 2) = w;
            } else {
                u16x4 w;
                #pragma unroll
                for (int reg = 0; reg < 4; ++reg) {
                    int rr = rbase + reg;
                    int t = rr / RP, v = rr - t * RP;
                    float val = acc[reg] + dbv;
                    w[reg] = f2b(val);
                    if (v < 25) { sd1 += val; sd2 += val * val; }
                }
                *(u16x4*)&xdst[(lr - 8) * 416 + rbase] = w;
            }
        }
    };

    __syncthreads();                           // init fence (once; no loads in flight)

    g1(0);
    asm volatile("s_waitcnt lgkmcnt(0)" ::: "memory");
    __builtin_amdgcn_s_barrier();
    __builtin_amdgcn_sched_barrier(0);

    for (int ch = 0; ch < 16; ++ch) {
        int t0 = ch * 16;
        char* bufr = x3Lb + (ch & 1) * BUF_B;
        // ---- xd compaction for chunk ch (wave-local; reads xdst before g1 overwrites)
        if (colt == 1) {
            int tofs = (wid >> 1) * 8;
            size_t gdb = (size_t)(n * O_ + o0) * TV + (size_t)(t0 + tofs) * V_;
            for (int q = lane; q < 200; q += 64) {
                int o = q / 25, w = q - o * 25;
                int g0 = w * 8;
                int tl2 = g0 / 25, v = g0 - tl2 * 25;
                u16x8 pk;
                #pragma unroll
                for (int k = 0; k < 8; ++k) {
                    pk[k] = xdst[o * 416 + (tofs + tl2) * RP + v];
                    if (++v == 25) { v = 0; ++tl2; }
                }
                *(u16x8*)&xdws[gdb + (size_t)o * TV + g0] = pk;
            }
        }
        // ---- GEMM1(ch+1): loads issue here, latency hides under GEMM2(ch)
        if (ch < 15) g1(ch + 1);
        // ---- GEMM2(ch) -> ystage (bf16)
        #pragma unroll
        for (int oi = 0; oi < 2; ++oi) {
            int ol = (wid << 1) + oi;
            const u32* L = (const u32*)(bufr + ol * OSTR_B);
            f32x4 acc0 = {0, 0, 0, 0}, acc1 = {0, 0, 0, 0};
            #pragma unroll
            for (int s = 0; s < 3; ++s) {
                const u32* Ls = L + s * 208 + rdw;
                u32 d0 = Ls[0], d1 = Ls[1], d8 = Ls[8], d9 = Ls[9];
                bf16x8 A = __builtin_bit_cast(bf16x8, u32x4{d0, d1, d8, d9});
                acc0 = mfma16(A, Bh[oi][s * 2 + 0], acc0);
                acc1 = mfma16(A, Bh[oi][s * 2 + 1], acc1);
            }
            int ylb = ol * 400 + (lg << 2) * 25;
            #pragma unroll
            for (int reg = 0; reg < 4; ++reg) {
                float v0 = acc0[reg] + rsb0[oi];
                ystage[ylb + reg * 25 + lr] = f2b(v0);
                sy1[oi] += v0; sy2[oi] += v0 * v0;
                if (lr < 9) {
                    float v1 = acc1[reg] + rsb1[oi];
                    ystage[ylb + reg * 25 + 16 + lr] = f2b(v1);
                    sy1[oi] += v1; sy2[oi] += v1 * v1;
                }
            }
        }
        // ---- y compaction (wave-local)
        {
            size_t ygb = (size_t)(n * O_ + o0) * TV + (size_t)t0 * V_;
            for (int q = lane; q < 100; q += 64) {
                int sel = q >= 50;
                int ol2 = (wid << 1) + sel;
                int j = q - sel * 50;
                u16x8 pk = *(const u16x8*)&ystage[ol2 * 400 + j * 8];
                *(u16x8*)&yb16[ygb + (size_t)ol2 * TV + j * 8] = pk;
            }
        }
        // ---- lgkm-only barrier: global loads stay in flight across it
        asm volatile("s_waitcnt lgkmcnt(0)" ::: "memory");
        __builtin_amdgcn_s_barrier();
        __builtin_amdgcn_sched_barrier(0);
    }
    // stats -> global atomics
    #pragma unroll
    for (int oi = 0; oi < 2; ++oi) {
        float v1 = sy1[oi], v2 = sy2[oi];
        #pragma unroll
        for (int m = 1; m < 64; m <<= 1) {
            v1 += __shfl_xor(v1, m);
            v2 += __shfl_xor(v2, m);
        }
        if (lane == 0) {
            atomicAdd(&stats[0 * O_ + o0 + (wid << 1) + oi], v1);
            atomicAdd(&stats[1 * O_ + o0 + (wid << 1) + oi], v2);
        }
    }
    if (colt == 1) {
        float v1 = sd1, v2 = sd2;
        v1 += __shfl_xor(v1, 16); v2 += __shfl_xor(v2, 16);
        v1 += __shfl_xor(v1, 32); v2 += __shfl_xor(v2, 32);
        if (lane >= 8 && lane < 16) {
            atomicAdd(&stats[2 * O_ + o0 + lane - 8], v1);
            atomicAdd(&stats[3 * O_ + o0 + lane - 8], v2);
        }
    }
}

// ---------------- K4: BN coefficients ----------------
__global__ void k4_coef(const float* __restrict__ bn_w, const float* __restrict__ bn_b,
                        const float* __restrict__ dbn_w, const float* __restrict__ dbn_b,
                        const float* __restrict__ stats, float* __restrict__ coef) {
    int o = threadIdx.x;
    if (o >= O_) return;
    float inv = 1.f / (float)(N_ * T_ * V_);
    float mu_y = stats[o] * inv;
    float var_y = stats[O_ + o] * inv - mu_y * mu_y;
    float ay = bn_w[o] * rsqrtf(var_y + 1e-5f);
    float by = bn_b[o] - mu_y * ay;
    float mu_d = stats[2 * O_ + o] * inv;
    float var_d = stats[3 * O_ + o] * inv - mu_d * mu_d;
    float ad = dbn_w[o] * rsqrtf(var_d + 1e-5f);
    float bd = dbn_b[o] - mu_d * ad;
    coef[o] = ay; coef[O_ + o] = by; coef[2 * O_ + o] = ad; coef[3 * O_ + o] = bd;
}

// ---------------- K5: final BN+residual+relu (y bf16 + xd bf16 -> out fp32) ----------------
__global__ void k5_final(float* __restrict__ out, const u16* __restrict__ yb,
                         const u16* __restrict__ xd, const float* __restrict__ cf) {
    size_t total = (size_t)N_ * O_ * TV / 8;
    for (size_t i = blockIdx.x * (size_t)blockDim.x + threadIdx.x; i < total;
         i += (size_t)gridDim.x * blockDim.x) {
        int o = (int)((i / 800) % O_);
        float ay = cf[o], by = cf[O_ + o], ad = cf[2 * O_ + o], bd = cf[3 * O_ + o];
        u16x8 yv = ((const u16x8*)yb)[i];
        u16x8 dv = ((const u16x8*)xd)[i];
        float4 r0, r1;
        r0.x = fmaxf(ay * b2f(yv[0]) + by + ad * b2f(dv[0]) + bd, 0.f);
        r0.y = fmaxf(ay * b2f(yv[1]) + by + ad * b2f(dv[1]) + bd, 0.f);
        r0.z = fmaxf(ay * b2f(yv[2]) + by + ad * b2f(dv[2]) + bd, 0.f);
        r0.w = fmaxf(ay * b2f(yv[3]) + by + ad * b2f(dv[3]) + bd, 0.f);
        r1.x = fmaxf(ay * b2f(yv[4]) + by + ad * b2f(dv[4]) + bd, 0.f);
        r1.y = fmaxf(ay * b2f(yv[5]) + by + ad * b2f(dv[5]) + bd, 0.f);
        r1.z = fmaxf(ay * b2f(yv[6]) + by + ad * b2f(dv[6]) + bd, 0.f);
        r1.w = fmaxf(ay * b2f(yv[7]) + by + ad * b2f(dv[7]) + bd, 0.f);
        ((float4*)out)[2 * i] = r0;
        ((float4*)out)[2 * i + 1] = r1;
    }
}

extern "C" void kernel_launch(void* const* d_in, const int* in_sizes, int n_in,
                              void* d_out, int out_size, void* d_ws, size_t ws_size,
                              hipStream_t stream) {
    const float* x     = (const float*)d_in[0];
    const float* spd   = (const float*)d_in[1];
    const float* A3    = (const float*)d_in[2];
    const float* A6    = (const float*)d_in[3];
    const float* w1    = (const float*)d_in[4];
    const float* b1    = (const float*)d_in[5];
    const float* w2    = (const float*)d_in[6];
    const float* b2    = (const float*)d_in[7];
    const float* w4    = (const float*)d_in[8];
    const float* b4    = (const float*)d_in[9];
    const float* w3    = (const float*)d_in[10];
    const float* b3    = (const float*)d_in[11];
    const float* alpha = (const float*)d_in[12];
    const float* beta  = (const float*)d_in[13];
    const float* gamma = (const float*)d_in[14];
    const float* bn_w  = (const float*)d_in[15];
    const float* bn_b  = (const float*)d_in[16];
    const float* dw    = (const float*)d_in[17];
    const float* db    = (const float*)d_in[18];
    const float* dbn_w = (const float*)d_in[19];
    const float* dbn_b = (const float*)d_in[20];
    float* out = (float*)d_out;
    u16*   wsu = (u16*)d_ws;
    float* wsf = (float*)d_ws;

    u16* a2f  = wsu + WS_A2F_U;
    u16* xq   = wsu + WS_XQ_U;
    u16* xd   = wsu + WS_XD_U;
    u16* yb   = wsu + WS_YB_U;
    float* xm    = wsf + WS_XM_F;
    float* rs    = wsf + WS_RS_F;
    float* stats = wsf + WS_STAT_F;
    float* coef  = wsf + WS_COEF_F;

    // zero rs_tot + stats (contiguous) — accumulated via atomics each call
    hipMemsetAsync(rs, 0, (N_ * O_ * V_ + 4 * O_) * sizeof(float), stream);

    k0_xq<<<N_ * 128, 256, 0, stream>>>(x, xq);
    k1_xm<<<N_ * 25, 256, 0, stream>>>(xq, xm);
    k2_a2f<<<N_ * S_ * 8, 256, 0, stream>>>(spd, A3, A6, w1, b1, w2, b2, w4, b4, b3,
                                            alpha, beta, gamma, a2f, xm, rs);
    k3_main<<<N_ * 24, 256, 0, stream>>>(xq, w3, dw, db, a2f, rs, yb, xd, stats);
    k4_coef<<<1, 256, 0, stream>>>(bn_w, bn_b, dbn_w, dbn_b, stats, coef);
    k5_final<<<4096, 256, 0, stream>>>(out, yb, xd, coef);
}

// Round 18
// 308.692 us; speedup vs baseline: 1.4673x; 1.0082x over previous
//
#include <hip/hip_runtime.h>

#define N_ 32
#define C_ 64
#define T_ 256
#define V_ 25
#define O_ 192
#define S_ 3
#define R_ 8
#define VV (V_*V_)      // 625
#define TV (T_*V_)      // 6400
#define RP 26           // padded v-rows per t
#define TRP (T_*RP)     // 6656 rows per n

typedef unsigned short u16;
typedef unsigned int u32;
typedef __attribute__((ext_vector_type(4))) u16 u16x4;
typedef __attribute__((ext_vector_type(8))) u16 u16x8;
typedef __attribute__((ext_vector_type(4))) u32 u32x4;
typedef __attribute__((ext_vector_type(8))) __bf16 bf16x8;
typedef __attribute__((ext_vector_type(4))) float f32x4;

// ---- workspace layout (u16 units) ----
#define WS_A2F_U 0                                   // N*O*6*64*8 = 18,874,368
#define WS_XQ_U  (18874368)                          // 13,631,488
#define WS_XD_U  (18874368 + 13631488)               // 39,321,600
#define WS_YB_U  (18874368 + 13631488 + 39321600)    // 39,321,600 (y as bf16)
// float region (after 111,149,056 u16):
#define WS_XM_F   (55574528)                         // N*C*V = 51,200
#define WS_RS_F   (55574528 + 51200)                 // N*O*V = 153,600
#define WS_STAT_F (55574528 + 51200 + 153600)        // 4*O

__device__ __forceinline__ u16 f2b(float f) {
    return __builtin_bit_cast(u16, (__bf16)f);
}
__device__ __forceinline__ float b2f(u16 u) {
    return __builtin_bit_cast(float, ((unsigned)u) << 16);
}
__device__ __forceinline__ f32x4 mfma16(bf16x8 a, bf16x8 b, f32x4 c) {
    return __builtin_amdgcn_mfma_f32_16x16x32_bf16(a, b, c, 0, 0, 0);
}
__device__ __forceinline__ float fast_tanh(float x) {
    // tanh(x) = 1 - 2/(e^{2x}+1); saturates correctly at +-inf
    return 1.f - 2.f * __builtin_amdgcn_rcpf(__expf(2.f * x) + 1.f);
}

// ---------------- K0: x[n,c,t,v] fp32 -> xq[n][t*26+v][c' perm] bf16 ----------------
__global__ void k0_xq(const float* __restrict__ x, u16* __restrict__ xq) {
    __shared__ float tile[64][52];
    int bid = blockIdx.x;
    int n = bid >> 7, tb = bid & 127;
    int t0 = tb * 2;
    int tid = threadIdx.x;
    const float2* xp = (const float2*)(x + (size_t)n * C_ * TV + t0 * 25);
    for (int p = tid; p < 1600; p += 256) {
        int c = p / 25, q = p % 25;
        float2 f2 = xp[(size_t)c * 3200 + q];
        tile[c][q * 2] = f2.x;
        tile[c][q * 2 + 1] = f2.y;
    }
    __syncthreads();
    for (int p = tid; p < 832; p += 256) {
        int row = p >> 4, c4g = p & 15;
        int t = row >= RP, v = row - t * RP;
        u16x4 w;
        #pragma unroll
        for (int i = 0; i < 4; ++i) {
            int co = ((c4g & 3) << 4) + ((c4g >> 2) << 2) + i;
            w[i] = (v < 25) ? f2b(tile[co][t * 25 + v]) : (u16)0;
        }
        *(u16x4*)&xq[((size_t)n * TRP + tb * 52 + row) * 64 + c4g * 4] = w;
    }
}

// ---------------- K1: xm[n,c,v] from xq (bf16, 26 MB) ----------------
__global__ void k1_xm(const u16* __restrict__ xq, float* __restrict__ xm_out) {
    __shared__ float ps[256];
    int bid = blockIdx.x;
    int n = bid / 25, v = bid % 25;
    int tid = threadIdx.x;
    int cg = tid & 63, tg = tid >> 6;
    const u16* p = xq + (size_t)n * TRP * 64 + ((size_t)(tg * 64 * RP + v)) * 64 + cg;
    float s = 0.f;
    for (int t = 0; t < 64; ++t) {
        s += b2f(*p);
        p += RP * 64;
    }
    ps[tid] = s;
    __syncthreads();
    if (tid < 64) {
        float tot = ps[tid] + ps[64 + tid] + ps[128 + tid] + ps[192 + tid];
        int c4g = tid >> 2, i = tid & 3;
        int co = ((c4g & 3) << 4) + ((c4g >> 2) << 2) + i;
        xm_out[((size_t)n * C_ + co) * V_ + v] = tot * (1.f / T_);
    }
}

// ---------------- K2: barrier-free per-wave A2F build + rs_tot (fast tanh) ----------------
__global__ void k2_a2f(const float* __restrict__ spd, const float* __restrict__ A3,
                       const float* __restrict__ A6,
                       const float* __restrict__ w1, const float* __restrict__ b1,
                       const float* __restrict__ w2, const float* __restrict__ b2,
                       const float* __restrict__ w4, const float* __restrict__ b4,
                       const float* __restrict__ b3,
                       const float* __restrict__ alpha, const float* __restrict__ beta,
                       const float* __restrict__ gamma,
                       u16* __restrict__ a2f, const float* __restrict__ xmbuf,
                       float* __restrict__ rs_tot) {
    __shared__ float xm[C_ * V_];
    __shared__ float x1s[R_ * V_], x2s[R_ * V_];
    __shared__ float dm[R_ * VV];
    __shared__ float a3s[VV], sps[VV];
    __shared__ float aatw[4][2 * VV];
    int bid = blockIdx.x;
    int n = bid / 24;
    int rem = bid % 24;
    int s = rem / 8, og = rem % 8;
    int tid = threadIdx.x, wid = tid >> 6, lane = tid & 63;
    const float* xmg = xmbuf + (size_t)n * C_ * V_;
    for (int p = tid; p < C_ * V_; p += 256) xm[p] = xmg[p];
    for (int p = tid; p < VV; p += 256) { a3s[p] = A3[s * VV + p]; sps[p] = spd[p]; }
    __syncthreads();
    if (tid < R_ * V_) {
        int r = tid / V_, v = tid % V_;
        float acc1 = b1[s * R_ + r], acc2 = b2[s * R_ + r];
        for (int c = 0; c < C_; ++c) {
            float xv = xm[c * V_ + v];
            acc1 += xv * w1[(s * R_ + r) * C_ + c];
            acc2 += xv * w2[(s * R_ + r) * C_ + c];
        }
        x1s[tid] = acc1; x2s[tid] = acc2;
    }
    __syncthreads();
    for (int p = tid; p < R_ * VV; p += 256) {
        int r = p / VV, uv = p % VV, u = uv / V_, v = uv % V_;
        dm[p] = fast_tanh(x1s[r * V_ + u] - x2s[r * V_ + v]);
    }
    __syncthreads();
    float al = alpha[0], be = beta[0], ga = gamma[0];
    float* aat = aatw[wid];
    for (int opi = 0; opi < 3; ++opi) {
        int op = wid * 3 + opi;
        int o0 = og * 24 + op * 2;
        float w4v[2][R_], b4v[2];
        #pragma unroll
        for (int oo = 0; oo < 2; ++oo) {
            b4v[oo] = b4[s * O_ + o0 + oo];
            #pragma unroll
            for (int r = 0; r < R_; ++r)
                w4v[oo][r] = w4[((size_t)(s * O_ + o0 + oo)) * R_ + r];
        }
        const float* a6p0 = A6 + ((o0 % 6) * VV);
        for (int p = lane; p < 2 * VV; p += 64) {
            int oo = p / VV, pp = p - oo * VV;
            float acc = b4v[oo];
            #pragma unroll
            for (int r = 0; r < R_; ++r) acc += dm[r * VV + pp] * w4v[oo][r];
            aat[p] = al * acc + a3s[pp] + ga * sps[pp] + be * a6p0[oo * VV + pp];
        }
        if (lane < 2 * V_) {
            int oo = lane / V_, u = lane - oo * V_;
            float rs = 0.f;
            for (int v = 0; v < V_; ++v) rs += aat[oo * VV + u * V_ + v];
            atomicAdd(&rs_tot[((size_t)(n * O_ + o0 + oo)) * V_ + u],
                      b3[s * O_ + o0 + oo] * rs);
        }
        #pragma unroll
        for (int it = 0; it < 4; ++it) {
            int idx = it * 64 + lane;
            int oo = idx >> 7, l2 = idx & 127, cu = l2 >> 6, l = l2 & 63;
            int u = cu * 16 + (l & 15);
            u16x8 w;
            #pragma unroll
            for (int j = 0; j < 8; ++j) {
                int v = ((j >> 2) << 4) + ((l >> 4) << 2) + (j & 3);
                float val = 0.f;
                if (u < V_ && v < V_) val = aat[oo * VV + u * V_ + v];
                w[j] = f2b(val);
            }
            size_t idxg = ((((size_t)(n * O_ + o0 + oo)) * S_ + s) * 2 + cu) * 64 + l;
            ((u16x8*)a2f)[idxg] = w;
        }
    }
}

// ---------------- K3: R16 champion (768-block convoy, dbuf, depth-4 prefetch) ----------------
#define OSTR_B 2504          // /4 = 626 ≡ 18 (mod 32)
#define SSTR_B 832           // 416 rows * 2B
#define BUF_B  20064         // 8*2504 + 32 pad

__global__ __launch_bounds__(256, 3)
void k3_main(const u16* __restrict__ xq,
             const float* __restrict__ w3, const float* __restrict__ dw,
             const float* __restrict__ db,
             const u16* __restrict__ a2f, const float* __restrict__ rs_tot,
             u16* __restrict__ yb16, u16* __restrict__ xdws,
             float* __restrict__ stats) {
    __shared__ char x3Lb[2 * BUF_B];    // 40,128 B
    __shared__ u16 xdst[8 * 416];       //  6,656 B
    __shared__ u16 ystage[8 * 400];     //  6,400 B
    int orig = blockIdx.x;
    int bid = (orig & 7) * 96 + (orig >> 3);   // same-n blocks -> same XCD
    int n = bid / 24;
    int o0 = (bid % 24) * 8;
    int tid = threadIdx.x, wid = tid >> 6, lane = tid & 63;
    int lr = lane & 15, lg = lane >> 4;
    int colt = wid & 1;
    int rt0 = (wid >> 1) * 13;

    for (int p = tid; p < 2 * BUF_B / 16; p += 256) ((u32x4*)x3Lb)[p] = u32x4{0,0,0,0};

    const float* wsrc = (colt == 0)
        ? w3 + ((size_t)((lr >> 3) * O_ + o0 + (lr & 7))) * C_
        : ((lr < 8) ? w3 + ((size_t)(2 * O_ + o0 + lr)) * C_
                    : dw + ((size_t)(o0 + lr - 8)) * C_);
    bf16x8 bw[2];
    #pragma unroll
    for (int ks = 0; ks < 2; ++ks) {
        u16x8 tmp;
        #pragma unroll
        for (int j = 0; j < 8; ++j) {
            int c = ks * 32 + (lg << 2) + (j & 3) + ((j >> 2) << 4);
            tmp[j] = f2b(wsrc[c]);
        }
        bw[ks] = __builtin_bit_cast(bf16x8, tmp);
    }
    float dbv = (colt == 1 && lr >= 8) ? db[o0 + lr - 8] : 0.f;

    int wo = (colt == 0) ? (lr & 7) : lr;
    int wsb = (colt == 0) ? (lr >> 3) : 2;
    int colbyte = wo * OSTR_B + wsb * SSTR_B;

    const bf16x8* a2v = (const bf16x8*)a2f;
    bf16x8 Bh[2][6];
    float rsb0[2], rsb1[2];
    #pragma unroll
    for (int oi = 0; oi < 2; ++oi) {
        int o = o0 + (wid << 1) + oi;
        const bf16x8* bp = a2v + ((size_t)(n * O_ + o)) * 6 * 64 + lane;
        #pragma unroll
        for (int q = 0; q < 6; ++q) Bh[oi][q] = bp[(size_t)q * 64];
        const float* rsp = rs_tot + ((size_t)(n * O_ + o)) * V_;
        rsb0[oi] = rsp[lr];
        rsb1[oi] = (lr < 9) ? rsp[16 + lr] : 0.f;
    }

    float sy1[2] = {0, 0}, sy2[2] = {0, 0};
    float sd1 = 0.f, sd2 = 0.f;
    const u16* xbn = xq + (size_t)n * TRP * 64;
    int rdw = 13 * lr + 2 * lg;
    char* buf = x3Lb;
    int t0 = 0;

    auto tl = [&](int ch, int j, u16x8& A0, u16x8& A1) {
        const u16* p = xbn + ((size_t)(ch * 16) * RP + (size_t)((rt0 + j) * 16 + lr)) * 64
                       + (lg << 4);
        A0 = *(const u16x8*)p;
        A1 = *(const u16x8*)(p + 8);
    };
    auto proc = [&](int rt, u16x8 A0, u16x8 A1) {
        f32x4 acc = {0.f, 0.f, 0.f, 0.f};
        acc = mfma16(__builtin_bit_cast(bf16x8, A0), bw[0], acc);
        acc = mfma16(__builtin_bit_cast(bf16x8, A1), bw[1], acc);
        int rbase = rt * 16 + (lg << 2);
        if (colt == 0 || lr < 8) {
            u16x4 w;
            #pragma unroll
            for (int reg = 0; reg < 4; ++reg) w[reg] = f2b(acc[reg]);
            *(u16x4*)(buf + colbyte + rbase * 2) = w;
        } else {
            u16x4 w;
            #pragma unroll
            for (int reg = 0; reg < 4; ++reg) {
                int rr = rbase + reg;
                int t = rr / RP, v = rr - t * RP;
                float val = acc[reg] + dbv;
                w[reg] = f2b(val);
                if (v < 25) { sd1 += val; sd2 += val * val; }
            }
            *(u16x4*)&xdst[(lr - 8) * 416 + rbase] = w;
        }
    };

    __syncthreads();                           // init fence

    u16x8 p0a, p0b, p1a, p1b, p2a, p2b, p3a, p3b;
    tl(0, 0, p0a, p0b); tl(0, 1, p1a, p1b); tl(0, 2, p2a, p2b); tl(0, 3, p3a, p3b);

    for (int ch = 0; ch < 16; ++ch) {
        t0 = ch * 16;
        buf = x3Lb + (ch & 1) * BUF_B;
        // ---- GEMM1: peeled prefetched tiles 0..3, then in-chunk 4..12
        proc(rt0 + 0, p0a, p0b);
        proc(rt0 + 1, p1a, p1b);
        proc(rt0 + 2, p2a, p2b);
        proc(rt0 + 3, p3a, p3b);
        for (int j = 4; j < 13; ++j) {
            u16x8 A0, A1;
            tl(ch, j, A0, A1);
            proc(rt0 + j, A0, A1);
        }
        // prefetch next chunk's tiles 0..3 (in flight across barrier + GEMM2)
        if (ch < 15) {
            tl(ch + 1, 0, p0a, p0b); tl(ch + 1, 1, p1a, p1b);
            tl(ch + 1, 2, p2a, p2b); tl(ch + 1, 3, p3a, p3b);
        }
        __syncthreads();   // x3/xdst handoff; dbuf covers write-after-read
        // ---- GEMM2 -> ystage (bf16)
        #pragma unroll
        for (int oi = 0; oi < 2; ++oi) {
            int ol = (wid << 1) + oi;
            const u32* L = (const u32*)(buf + ol * OSTR_B);
            f32x4 acc0 = {0, 0, 0, 0}, acc1 = {0, 0, 0, 0};
            #pragma unroll
            for (int s = 0; s < 3; ++s) {
                const u32* Ls = L + s * 208 + rdw;
                u32 d0 = Ls[0], d1 = Ls[1], d8 = Ls[8], d9 = Ls[9];
                bf16x8 A = __builtin_bit_cast(bf16x8, u32x4{d0, d1, d8, d9});
                acc0 = mfma16(A, Bh[oi][s * 2 + 0], acc0);
                acc1 = mfma16(A, Bh[oi][s * 2 + 1], acc1);
            }
            int ylb = ol * 400 + (lg << 2) * 25;
            #pragma unroll
            for (int reg = 0; reg < 4; ++reg) {
                float v0 = acc0[reg] + rsb0[oi];
                ystage[ylb + reg * 25 + lr] = f2b(v0);
                sy1[oi] += v0; sy2[oi] += v0 * v0;
                if (lr < 9) {
                    float v1 = acc1[reg] + rsb1[oi];
                    ystage[ylb + reg * 25 + 16 + lr] = f2b(v1);
                    sy1[oi] += v1; sy2[oi] += v1 * v1;
                }
            }
        }
        // ---- per-wave y compaction: coalesced 16B stores of own 2 o's
        {
            size_t ygb = (size_t)(n * O_ + o0) * TV + (size_t)t0 * V_;
            for (int q = lane; q < 100; q += 64) {
                int sel = q >= 50;
                int ol2 = (wid << 1) + sel;
                int j = q - sel * 50;
                u16x8 pk = *(const u16x8*)&ystage[ol2 * 400 + j * 8];
                *(u16x8*)&yb16[ygb + (size_t)ol2 * TV + j * 8] = pk;
            }
        }
        // ---- per-wave xd compaction (colt1 waves own their staged halves)
        if (colt == 1) {
            int tofs = (wid >> 1) * 8;
            size_t gdb = (size_t)(n * O_ + o0) * TV + (size_t)(t0 + tofs) * V_;
            for (int q = lane; q < 200; q += 64) {
                int o = q / 25, w = q - o * 25;
                int g0 = w * 8;
                int tl2 = g0 / 25, v = g0 - tl2 * 25;
                u16x8 pk;
                #pragma unroll
                for (int k = 0; k < 8; ++k) {
                    pk[k] = xdst[o * 416 + (tofs + tl2) * RP + v];
                    if (++v == 25) { v = 0; ++tl2; }
                }
                *(u16x8*)&xdws[gdb + (size_t)o * TV + g0] = pk;
            }
        }
    }
    // stats -> global atomics
    #pragma unroll
    for (int oi = 0; oi < 2; ++oi) {
        float v1 = sy1[oi], v2 = sy2[oi];
        #pragma unroll
        for (int m = 1; m < 64; m <<= 1) {
            v1 += __shfl_xor(v1, m);
            v2 += __shfl_xor(v2, m);
        }
        if (lane == 0) {
            atomicAdd(&stats[0 * O_ + o0 + (wid << 1) + oi], v1);
            atomicAdd(&stats[1 * O_ + o0 + (wid << 1) + oi], v2);
        }
    }
    if (colt == 1) {
        float v1 = sd1, v2 = sd2;
        v1 += __shfl_xor(v1, 16); v2 += __shfl_xor(v2, 16);
        v1 += __shfl_xor(v1, 32); v2 += __shfl_xor(v2, 32);
        if (lane >= 8 && lane < 16) {
            atomicAdd(&stats[2 * O_ + o0 + lane - 8], v1);
            atomicAdd(&stats[3 * O_ + o0 + lane - 8], v2);
        }
    }
}

// ---------------- K5: BN coefs (from stats, in-block) + BN+residual+relu ----------------
__global__ void k5_final(float* __restrict__ out, const u16* __restrict__ yb,
                         const u16* __restrict__ xd, const float* __restrict__ stats,
                         const float* __restrict__ bn_w, const float* __restrict__ bn_b,
                         const float* __restrict__ dbn_w, const float* __restrict__ dbn_b) {
    __shared__ float cf[4 * O_];
    int tid = threadIdx.x;
    if (tid < O_) {
        int o = tid;
        float inv = 1.f / (float)(N_ * T_ * V_);
        float mu_y = stats[o] * inv;
        float var_y = stats[O_ + o] * inv - mu_y * mu_y;
        float ay = bn_w[o] * rsqrtf(var_y + 1e-5f);
        float by = bn_b[o] - mu_y * ay;
        float mu_d = stats[2 * O_ + o] * inv;
        float var_d = stats[3 * O_ + o] * inv - mu_d * mu_d;
        float ad = dbn_w[o] * rsqrtf(var_d + 1e-5f);
        float bd = dbn_b[o] - mu_d * ad;
        cf[o] = ay; cf[O_ + o] = by; cf[2 * O_ + o] = ad; cf[3 * O_ + o] = bd;
    }
    __syncthreads();
    size_t total = (size_t)N_ * O_ * TV / 8;
    for (size_t i = blockIdx.x * (size_t)blockDim.x + tid; i < total;
         i += (size_t)gridDim.x * blockDim.x) {
        int o = (int)((i / 800) % O_);
        float ay = cf[o], by = cf[O_ + o], ad = cf[2 * O_ + o], bd = cf[3 * O_ + o];
        u16x8 yv = ((const u16x8*)yb)[i];
        u16x8 dv = ((const u16x8*)xd)[i];
        float4 r0, r1;
        r0.x = fmaxf(ay * b2f(yv[0]) + by + ad * b2f(dv[0]) + bd, 0.f);
        r0.y = fmaxf(ay * b2f(yv[1]) + by + ad * b2f(dv[1]) + bd, 0.f);
        r0.z = fmaxf(ay * b2f(yv[2]) + by + ad * b2f(dv[2]) + bd, 0.f);
        r0.w = fmaxf(ay * b2f(yv[3]) + by + ad * b2f(dv[3]) + bd, 0.f);
        r1.x = fmaxf(ay * b2f(yv[4]) + by + ad * b2f(dv[4]) + bd, 0.f);
        r1.y = fmaxf(ay * b2f(yv[5]) + by + ad * b2f(dv[5]) + bd, 0.f);
        r1.z = fmaxf(ay * b2f(yv[6]) + by + ad * b2f(dv[6]) + bd, 0.f);
        r1.w = fmaxf(ay * b2f(yv[7]) + by + ad * b2f(dv[7]) + bd, 0.f);
        ((float4*)out)[2 * i] = r0;
        ((float4*)out)[2 * i + 1] = r1;
    }
}

extern "C" void kernel_launch(void* const* d_in, const int* in_sizes, int n_in,
                              void* d_out, int out_size, void* d_ws, size_t ws_size,
                              hipStream_t stream) {
    const float* x     = (const float*)d_in[0];
    const float* spd   = (const float*)d_in[1];
    const float* A3    = (const float*)d_in[2];
    const float* A6    = (const float*)d_in[3];
    const float* w1    = (const float*)d_in[4];
    const float* b1    = (const float*)d_in[5];
    const float* w2    = (const float*)d_in[6];
    const float* b2    = (const float*)d_in[7];
    const float* w4    = (const float*)d_in[8];
    const float* b4    = (const float*)d_in[9];
    const float* w3    = (const float*)d_in[10];
    const float* b3    = (const float*)d_in[11];
    const float* alpha = (const float*)d_in[12];
    const float* beta  = (const float*)d_in[13];
    const float* gamma = (const float*)d_in[14];
    const float* bn_w  = (const float*)d_in[15];
    const float* bn_b  = (const float*)d_in[16];
    const float* dw    = (const float*)d_in[17];
    const float* db    = (const float*)d_in[18];
    const float* dbn_w = (const float*)d_in[19];
    const float* dbn_b = (const float*)d_in[20];
    float* out = (float*)d_out;
    u16*   wsu = (u16*)d_ws;
    float* wsf = (float*)d_ws;

    u16* a2f  = wsu + WS_A2F_U;
    u16* xq   = wsu + WS_XQ_U;
    u16* xd   = wsu + WS_XD_U;
    u16* yb   = wsu + WS_YB_U;
    float* xm    = wsf + WS_XM_F;
    float* rs    = wsf + WS_RS_F;
    float* stats = wsf + WS_STAT_F;

    // zero rs_tot + stats (contiguous) — accumulated via atomics each call
    hipMemsetAsync(rs, 0, (N_ * O_ * V_ + 4 * O_) * sizeof(float), stream);

    k0_xq<<<N_ * 128, 256, 0, stream>>>(x, xq);
    k1_xm<<<N_ * 25, 256, 0, stream>>>(xq, xm);
    k2_a2f<<<N_ * S_ * 8, 256, 0, stream>>>(spd, A3, A6, w1, b1, w2, b2, w4, b4, b3,
                                            alpha, beta, gamma, a2f, xm, rs);
    k3_main<<<N_ * 24, 256, 0, stream>>>(xq, w3, dw, db, a2f, rs, yb, xd, stats);
    k5_final<<<4096, 256, 0, stream>>>(out, yb, xd, stats, bn_w, bn_b, dbn_w, dbn_b);
}

// Round 19
// 302.276 us; speedup vs baseline: 1.4984x; 1.0212x over previous
//
#include <hip/hip_runtime.h>

#define N_ 32
#define C_ 64
#define T_ 256
#define V_ 25
#define O_ 192
#define S_ 3
#define R_ 8
#define VV (V_*V_)      // 625
#define TV (T_*V_)      // 6400
#define RP 26           // padded v-rows per t
#define TRP (T_*RP)     // 6656 rows per n

typedef unsigned short u16;
typedef unsigned int u32;
typedef __attribute__((ext_vector_type(4))) u16 u16x4;
typedef __attribute__((ext_vector_type(8))) u16 u16x8;
typedef __attribute__((ext_vector_type(4))) u32 u32x4;
typedef __attribute__((ext_vector_type(8))) __bf16 bf16x8;
typedef __attribute__((ext_vector_type(4))) float f32x4;

// ---- workspace layout (u16 units) ----
#define WS_A2F_U 0                                   // N*O*6*64*8 = 18,874,368
#define WS_XQ_U  (18874368)                          // 13,631,488
#define WS_XD_U  (18874368 + 13631488)               // 39,321,600
#define WS_YB_U  (18874368 + 13631488 + 39321600)    // 39,321,600 (y as bf16)
// float region (after 111,149,056 u16):
#define WS_XM_F   (55574528)                         // N*C*V = 51,200
#define WS_RS_F   (55574528 + 51200)                 // N*O*V = 153,600
#define WS_STAT_F (55574528 + 51200 + 153600)        // 4*O

__device__ __forceinline__ u16 f2b(float f) {
    return __builtin_bit_cast(u16, (__bf16)f);
}
__device__ __forceinline__ float b2f(u16 u) {
    return __builtin_bit_cast(float, ((unsigned)u) << 16);
}
__device__ __forceinline__ f32x4 mfma16(bf16x8 a, bf16x8 b, f32x4 c) {
    return __builtin_amdgcn_mfma_f32_16x16x32_bf16(a, b, c, 0, 0, 0);
}
__device__ __forceinline__ float fast_tanh(float x) {
    return 1.f - 2.f * __builtin_amdgcn_rcpf(__expf(2.f * x) + 1.f);
}

// ---------------- K0: x[n,c,t,v] fp32 -> xq[n][t*26+v][c' perm] bf16 ----------------
__global__ void k0_xq(const float* __restrict__ x, u16* __restrict__ xq) {
    __shared__ float tile[64][52];
    int bid = blockIdx.x;
    int n = bid >> 7, tb = bid & 127;
    int t0 = tb * 2;
    int tid = threadIdx.x;
    const float2* xp = (const float2*)(x + (size_t)n * C_ * TV + t0 * 25);
    for (int p = tid; p < 1600; p += 256) {
        int c = p / 25, q = p % 25;
        float2 f2 = xp[(size_t)c * 3200 + q];
        tile[c][q * 2] = f2.x;
        tile[c][q * 2 + 1] = f2.y;
    }
    __syncthreads();
    for (int p = tid; p < 832; p += 256) {
        int row = p >> 4, c4g = p & 15;
        int t = row >= RP, v = row - t * RP;
        u16x4 w;
        #pragma unroll
        for (int i = 0; i < 4; ++i) {
            int co = ((c4g & 3) << 4) + ((c4g >> 2) << 2) + i;
            w[i] = (v < 25) ? f2b(tile[co][t * 25 + v]) : (u16)0;
        }
        *(u16x4*)&xq[((size_t)n * TRP + tb * 52 + row) * 64 + c4g * 4] = w;
    }
}

// ---------------- K1: xm[n,c,v] from xq (bf16, 26 MB) ----------------
__global__ void k1_xm(const u16* __restrict__ xq, float* __restrict__ xm_out) {
    __shared__ float ps[256];
    int bid = blockIdx.x;
    int n = bid / 25, v = bid % 25;
    int tid = threadIdx.x;
    int cg = tid & 63, tg = tid >> 6;
    const u16* p = xq + (size_t)n * TRP * 64 + ((size_t)(tg * 64 * RP + v)) * 64 + cg;
    float s = 0.f;
    for (int t = 0; t < 64; ++t) {
        s += b2f(*p);
        p += RP * 64;
    }
    ps[tid] = s;
    __syncthreads();
    if (tid < 64) {
        float tot = ps[tid] + ps[64 + tid] + ps[128 + tid] + ps[192 + tid];
        int c4g = tid >> 2, i = tid & 3;
        int co = ((c4g & 3) << 4) + ((c4g >> 2) << 2) + i;
        xm_out[((size_t)n * C_ + co) * V_ + v] = tot * (1.f / T_);
    }
}

// ---------------- K2: barrier-free per-wave A2F build + rs_tot (fast tanh) ----------------
__global__ void k2_a2f(const float* __restrict__ spd, const float* __restrict__ A3,
                       const float* __restrict__ A6,
                       const float* __restrict__ w1, const float* __restrict__ b1,
                       const float* __restrict__ w2, const float* __restrict__ b2,
                       const float* __restrict__ w4, const float* __restrict__ b4,
                       const float* __restrict__ b3,
                       const float* __restrict__ alpha, const float* __restrict__ beta,
                       const float* __restrict__ gamma,
                       u16* __restrict__ a2f, const float* __restrict__ xmbuf,
                       float* __restrict__ rs_tot) {
    __shared__ float xm[C_ * V_];
    __shared__ float x1s[R_ * V_], x2s[R_ * V_];
    __shared__ float dm[R_ * VV];
    __shared__ float a3s[VV], sps[VV];
    __shared__ float aatw[4][2 * VV];
    int bid = blockIdx.x;
    int n = bid / 24;
    int rem = bid % 24;
    int s = rem / 8, og = rem % 8;
    int tid = threadIdx.x, wid = tid >> 6, lane = tid & 63;
    const float* xmg = xmbuf + (size_t)n * C_ * V_;
    for (int p = tid; p < C_ * V_; p += 256) xm[p] = xmg[p];
    for (int p = tid; p < VV; p += 256) { a3s[p] = A3[s * VV + p]; sps[p] = spd[p]; }
    __syncthreads();
    if (tid < R_ * V_) {
        int r = tid / V_, v = tid % V_;
        float acc1 = b1[s * R_ + r], acc2 = b2[s * R_ + r];
        for (int c = 0; c < C_; ++c) {
            float xv = xm[c * V_ + v];
            acc1 += xv * w1[(s * R_ + r) * C_ + c];
            acc2 += xv * w2[(s * R_ + r) * C_ + c];
        }
        x1s[tid] = acc1; x2s[tid] = acc2;
    }
    __syncthreads();
    for (int p = tid; p < R_ * VV; p += 256) {
        int r = p / VV, uv = p % VV, u = uv / V_, v = uv % V_;
        dm[p] = fast_tanh(x1s[r * V_ + u] - x2s[r * V_ + v]);
    }
    __syncthreads();
    float al = alpha[0], be = beta[0], ga = gamma[0];
    float* aat = aatw[wid];
    for (int opi = 0; opi < 3; ++opi) {
        int op = wid * 3 + opi;
        int o0 = og * 24 + op * 2;
        float w4v[2][R_], b4v[2];
        #pragma unroll
        for (int oo = 0; oo < 2; ++oo) {
            b4v[oo] = b4[s * O_ + o0 + oo];
            #pragma unroll
            for (int r = 0; r < R_; ++r)
                w4v[oo][r] = w4[((size_t)(s * O_ + o0 + oo)) * R_ + r];
        }
        const float* a6p0 = A6 + ((o0 % 6) * VV);
        for (int p = lane; p < 2 * VV; p += 64) {
            int oo = p / VV, pp = p - oo * VV;
            float acc = b4v[oo];
            #pragma unroll
            for (int r = 0; r < R_; ++r) acc += dm[r * VV + pp] * w4v[oo][r];
            aat[p] = al * acc + a3s[pp] + ga * sps[pp] + be * a6p0[oo * VV + pp];
        }
        if (lane < 2 * V_) {
            int oo = lane / V_, u = lane - oo * V_;
            float rs = 0.f;
            for (int v = 0; v < V_; ++v) rs += aat[oo * VV + u * V_ + v];
            atomicAdd(&rs_tot[((size_t)(n * O_ + o0 + oo)) * V_ + u],
                      b3[s * O_ + o0 + oo] * rs);
        }
        #pragma unroll
        for (int it = 0; it < 4; ++it) {
            int idx = it * 64 + lane;
            int oo = idx >> 7, l2 = idx & 127, cu = l2 >> 6, l = l2 & 63;
            int u = cu * 16 + (l & 15);
            u16x8 w;
            #pragma unroll
            for (int j = 0; j < 8; ++j) {
                int v = ((j >> 2) << 4) + ((l >> 4) << 2) + (j & 3);
                float val = 0.f;
                if (u < V_ && v < V_) val = aat[oo * VV + u * V_ + v];
                w[j] = f2b(val);
            }
            size_t idxg = ((((size_t)(n * O_ + o0 + oo)) * S_ + s) * 2 + cu) * 64 + l;
            ((u16x8*)a2f)[idxg] = w;
        }
    }
}

// ---------------- K3: 8-wave (512-thread) blocks, same 768-block convoy ----------------
// grid N*24 = 768 (3 blocks/CU, 24 waves/CU). 2 barriers/chunk; dbuf x3.
// Wave map: colt=wid&1, tq=wid>>1 -> GEMM1 tiles {7,7,6,6}; GEMM2: o = o0+wid.
#define OSTR_B 2504          // /4 = 626 ≡ 18 (mod 32)
#define SSTR_B 832           // 416 rows * 2B
#define BUF_B  20064         // 8*2504 + 32 pad

__global__ __launch_bounds__(512, 6)
void k3_main(const u16* __restrict__ xq,
             const float* __restrict__ w3, const float* __restrict__ dw,
             const float* __restrict__ db,
             const u16* __restrict__ a2f, const float* __restrict__ rs_tot,
             u16* __restrict__ yb16, u16* __restrict__ xdws,
             float* __restrict__ stats) {
    __shared__ char x3Lb[2 * BUF_B];    // 40,128 B
    __shared__ u16 xdst[8 * 416];       //  6,656 B
    __shared__ u16 ystage[8 * 400];     //  6,400 B
    int orig = blockIdx.x;
    int bid = (orig & 7) * 96 + (orig >> 3);   // same-n blocks -> same XCD
    int n = bid / 24;
    int o0 = (bid % 24) * 8;
    int tid = threadIdx.x, wid = tid >> 6, lane = tid & 63;
    int lr = lane & 15, lg = lane >> 4;
    int colt = wid & 1;
    int tq = wid >> 1;
    int rt0 = tq * 7 - (tq == 3 ? 1 : 0);      // {0,7,14,20}
    int cnt = (tq < 2) ? 7 : 6;

    for (int p = tid; p < 2 * BUF_B / 16; p += 512) ((u32x4*)x3Lb)[p] = u32x4{0,0,0,0};

    // GEMM1 B-frags: colt0 = (s0,o0..7)|(s1,o0..7); colt1 = (s2,o0..7)|(down,o0..7)
    const float* wsrc = (colt == 0)
        ? w3 + ((size_t)((lr >> 3) * O_ + o0 + (lr & 7))) * C_
        : ((lr < 8) ? w3 + ((size_t)(2 * O_ + o0 + lr)) * C_
                    : dw + ((size_t)(o0 + lr - 8)) * C_);
    bf16x8 bw[2];
    #pragma unroll
    for (int ks = 0; ks < 2; ++ks) {
        u16x8 tmp;
        #pragma unroll
        for (int j = 0; j < 8; ++j) {
            int c = ks * 32 + (lg << 2) + (j & 3) + ((j >> 2) << 4);
            tmp[j] = f2b(wsrc[c]);
        }
        bw[ks] = __builtin_bit_cast(bf16x8, tmp);
    }
    float dbv = (colt == 1 && lr >= 8) ? db[o0 + lr - 8] : 0.f;

    int wo = (colt == 0) ? (lr & 7) : lr;
    int wsb = (colt == 0) ? (lr >> 3) : 2;
    int colbyte = wo * OSTR_B + wsb * SSTR_B;

    // GEMM2: wave owns o = o0 + wid
    const bf16x8* a2v = (const bf16x8*)a2f;
    bf16x8 Bh[6];
    float rsb0, rsb1;
    {
        int o = o0 + wid;
        const bf16x8* bp = a2v + ((size_t)(n * O_ + o)) * 6 * 64 + lane;
        #pragma unroll
        for (int q = 0; q < 6; ++q) Bh[q] = bp[(size_t)q * 64];
        const float* rsp = rs_tot + ((size_t)(n * O_ + o)) * V_;
        rsb0 = rsp[lr];
        rsb1 = (lr < 9) ? rsp[16 + lr] : 0.f;
    }

    float sy1 = 0.f, sy2 = 0.f;
    float sd1 = 0.f, sd2 = 0.f;
    const u16* xbn = xq + (size_t)n * TRP * 64;
    int rdw = 13 * lr + 2 * lg;

    __syncthreads();                           // init fence

    for (int ch = 0; ch < 16; ++ch) {
        int t0 = ch * 16;
        char* buf = x3Lb + (ch & 1) * BUF_B;
        const u16* xrow = xbn + (size_t)t0 * RP * 64;
        // ---- GEMM1: wave's tile range, demand loads (TLP hides latency)
        for (int j = 0; j < cnt; ++j) {
            int rt = rt0 + j;
            const u16* ap = xrow + (size_t)(rt * 16 + lr) * 64 + (lg << 4);
            u16x8 A0 = *(const u16x8*)ap;
            u16x8 A1 = *(const u16x8*)(ap + 8);
            f32x4 acc = {0.f, 0.f, 0.f, 0.f};
            acc = mfma16(__builtin_bit_cast(bf16x8, A0), bw[0], acc);
            acc = mfma16(__builtin_bit_cast(bf16x8, A1), bw[1], acc);
            int rbase = rt * 16 + (lg << 2);
            if (colt == 0 || lr < 8) {
                u16x4 w;
                #pragma unroll
                for (int reg = 0; reg < 4; ++reg) w[reg] = f2b(acc[reg]);
                *(u16x4*)(buf + colbyte + rbase * 2) = w;
            } else {
                u16x4 w;
                #pragma unroll
                for (int reg = 0; reg < 4; ++reg) {
                    int rr = rbase + reg;
                    int t = rr / RP, v = rr - t * RP;
                    float val = acc[reg] + dbv;
                    w[reg] = f2b(val);
                    if (v < 25) { sd1 += val; sd2 += val * val; }
                }
                *(u16x4*)&xdst[(lr - 8) * 416 + rbase] = w;
            }
        }
        __syncthreads();   // barrier 1: x3/xdst handoff
        // ---- GEMM2 -> ystage (bf16): wave's single o
        {
            const u32* L = (const u32*)(buf + wid * OSTR_B);
            f32x4 acc0 = {0, 0, 0, 0}, acc1 = {0, 0, 0, 0};
            #pragma unroll
            for (int s = 0; s < 3; ++s) {
                const u32* Ls = L + s * 208 + rdw;
                u32 d0 = Ls[0], d1 = Ls[1], d8 = Ls[8], d9 = Ls[9];
                bf16x8 A = __builtin_bit_cast(bf16x8, u32x4{d0, d1, d8, d9});
                acc0 = mfma16(A, Bh[s * 2 + 0], acc0);
                acc1 = mfma16(A, Bh[s * 2 + 1], acc1);
            }
            int ylb = wid * 400 + (lg << 2) * 25;
            #pragma unroll
            for (int reg = 0; reg < 4; ++reg) {
                float v0 = acc0[reg] + rsb0;
                ystage[ylb + reg * 25 + lr] = f2b(v0);
                sy1 += v0; sy2 += v0 * v0;
                if (lr < 9) {
                    float v1 = acc1[reg] + rsb1;
                    ystage[ylb + reg * 25 + 16 + lr] = f2b(v1);
                    sy1 += v1; sy2 += v1 * v1;
                }
            }
        }
        // ---- y compaction: wave's own o (wave-local ystage region)
        {
            size_t ygb = (size_t)(n * O_ + o0 + wid) * TV + (size_t)t0 * V_;
            if (lane < 50) {
                u16x8 pk = *(const u16x8*)&ystage[wid * 400 + lane * 8];
                *(u16x8*)&yb16[ygb + lane * 8] = pk;
            }
        }
        // ---- xd compaction: wave wid compacts o-local wid (cross-wave reads, post-barrier)
        {
            size_t gdb = (size_t)(n * O_ + o0 + wid) * TV + (size_t)t0 * V_;
            if (lane < 50) {
                int g0 = lane * 8;
                int tl2 = g0 / 25, v = g0 - tl2 * 25;
                u16x8 pk;
                #pragma unroll
                for (int k = 0; k < 8; ++k) {
                    pk[k] = xdst[wid * 416 + tl2 * RP + v];
                    if (++v == 25) { v = 0; ++tl2; }
                }
                *(u16x8*)&xdws[gdb + g0] = pk;
            }
        }
        __syncthreads();   // barrier 2: readers done before next GEMM1 overwrites
    }
    // stats -> global atomics
    {
        float v1 = sy1, v2 = sy2;
        #pragma unroll
        for (int m = 1; m < 64; m <<= 1) {
            v1 += __shfl_xor(v1, m);
            v2 += __shfl_xor(v2, m);
        }
        if (lane == 0) {
            atomicAdd(&stats[0 * O_ + o0 + wid], v1);
            atomicAdd(&stats[1 * O_ + o0 + wid], v2);
        }
    }
    if (colt == 1) {
        float v1 = sd1, v2 = sd2;
        v1 += __shfl_xor(v1, 16); v2 += __shfl_xor(v2, 16);
        v1 += __shfl_xor(v1, 32); v2 += __shfl_xor(v2, 32);
        if (lane >= 8 && lane < 16) {
            atomicAdd(&stats[2 * O_ + o0 + lane - 8], v1);
            atomicAdd(&stats[3 * O_ + o0 + lane - 8], v2);
        }
    }
}

// ---------------- K5: BN coefs (from stats, in-block) + BN+residual+relu ----------------
__global__ void k5_final(float* __restrict__ out, const u16* __restrict__ yb,
                         const u16* __restrict__ xd, const float* __restrict__ stats,
                         const float* __restrict__ bn_w, const float* __restrict__ bn_b,
                         const float* __restrict__ dbn_w, const float* __restrict__ dbn_b) {
    __shared__ float cf[4 * O_];
    int tid = threadIdx.x;
    if (tid < O_) {
        int o = tid;
        float inv = 1.f / (float)(N_ * T_ * V_);
        float mu_y = stats[o] * inv;
        float var_y = stats[O_ + o] * inv - mu_y * mu_y;
        float ay = bn_w[o] * rsqrtf(var_y + 1e-5f);
        float by = bn_b[o] - mu_y * ay;
        float mu_d = stats[2 * O_ + o] * inv;
        float var_d = stats[3 * O_ + o] * inv - mu_d * mu_d;
        float ad = dbn_w[o] * rsqrtf(var_d + 1e-5f);
        float bd = dbn_b[o] - mu_d * ad;
        cf[o] = ay; cf[O_ + o] = by; cf[2 * O_ + o] = ad; cf[3 * O_ + o] = bd;
    }
    __syncthreads();
    size_t total = (size_t)N_ * O_ * TV / 8;
    for (size_t i = blockIdx.x * (size_t)blockDim.x + tid; i < total;
         i += (size_t)gridDim.x * blockDim.x) {
        int o = (int)((i / 800) % O_);
        float ay = cf[o], by = cf[O_ + o], ad = cf[2 * O_ + o], bd = cf[3 * O_ + o];
        u16x8 yv = ((const u16x8*)yb)[i];
        u16x8 dv = ((const u16x8*)xd)[i];
        float4 r0, r1;
        r0.x = fmaxf(ay * b2f(yv[0]) + by + ad * b2f(dv[0]) + bd, 0.f);
        r0.y = fmaxf(ay * b2f(yv[1]) + by + ad * b2f(dv[1]) + bd, 0.f);
        r0.z = fmaxf(ay * b2f(yv[2]) + by + ad * b2f(dv[2]) + bd, 0.f);
        r0.w = fmaxf(ay * b2f(yv[3]) + by + ad * b2f(dv[3]) + bd, 0.f);
        r1.x = fmaxf(ay * b2f(yv[4]) + by + ad * b2f(dv[4]) + bd, 0.f);
        r1.y = fmaxf(ay * b2f(yv[5]) + by + ad * b2f(dv[5]) + bd, 0.f);
        r1.z = fmaxf(ay * b2f(yv[6]) + by + ad * b2f(dv[6]) + bd, 0.f);
        r1.w = fmaxf(ay * b2f(yv[7]) + by + ad * b2f(dv[7]) + bd, 0.f);
        ((float4*)out)[2 * i] = r0;
        ((float4*)out)[2 * i + 1] = r1;
    }
}

extern "C" void kernel_launch(void* const* d_in, const int* in_sizes, int n_in,
                              void* d_out, int out_size, void* d_ws, size_t ws_size,
                              hipStream_t stream) {
    const float* x     = (const float*)d_in[0];
    const float* spd   = (const float*)d_in[1];
    const float* A3    = (const float*)d_in[2];
    const float* A6    = (const float*)d_in[3];
    const float* w1    = (const float*)d_in[4];
    const float* b1    = (const float*)d_in[5];
    const float* w2    = (const float*)d_in[6];
    const float* b2    = (const float*)d_in[7];
    const float* w4    = (const float*)d_in[8];
    const float* b4    = (const float*)d_in[9];
    const float* w3    = (const float*)d_in[10];
    const float* b3    = (const float*)d_in[11];
    const float* alpha = (const float*)d_in[12];
    const float* beta  = (const float*)d_in[13];
    const float* gamma = (const float*)d_in[14];
    const float* bn_w  = (const float*)d_in[15];
    const float* bn_b  = (const float*)d_in[16];
    const float* dw    = (const float*)d_in[17];
    const float* db    = (const float*)d_in[18];
    const float* dbn_w = (const float*)d_in[19];
    const float* dbn_b = (const float*)d_in[20];
    float* out = (float*)d_out;
    u16*   wsu = (u16*)d_ws;
    float* wsf = (float*)d_ws;

    u16* a2f  = wsu + WS_A2F_U;
    u16* xq   = wsu + WS_XQ_U;
    u16* xd   = wsu + WS_XD_U;
    u16* yb   = wsu + WS_YB_U;
    float* xm    = wsf + WS_XM_F;
    float* rs    = wsf + WS_RS_F;
    float* stats = wsf + WS_STAT_F;

    // zero rs_tot + stats (contiguous) — accumulated via atomics each call
    hipMemsetAsync(rs, 0, (N_ * O_ * V_ + 4 * O_) * sizeof(float), stream);

    k0_xq<<<N_ * 128, 256, 0, stream>>>(x, xq);
    k1_xm<<<N_ * 25, 256, 0, stream>>>(xq, xm);
    k2_a2f<<<N_ * S_ * 8, 256, 0, stream>>>(spd, A3, A6, w1, b1, w2, b2, w4, b4, b3,
                                            alpha, beta, gamma, a2f, xm, rs);
    k3_main<<<N_ * 24, 512, 0, stream>>>(xq, w3, dw, db, a2f, rs, yb, xd, stats);
    k5_final<<<4096, 256, 0, stream>>>(out, yb, xd, stats, bn_w, bn_b, dbn_w, dbn_b);
}